// Round 1
// 304.367 us; speedup vs baseline: 1.0411x; 1.0411x over previous
//
#include <hip/hip_runtime.h>
#include <hip/hip_bf16.h>

// ---------------------------------------------------------------------------
// TwoLayerGCN. Round 17: fp8(e4m3) h1 for the layer-2 gather.
// R16 analysis: spmm256 FETCH (174.6MB) == compulsory bound for per-XCD row
// replication (50000 rows x (1-e^-2) x 512B x 8 XCDs ~= 177MB) -> cache is
// optimal; only fewer bytes/row can cut it. h1 stored as fp8 e4m3 (hw
// v_cvt_pk_f32_fp8 on gather, v_cvt_pk_fp8_f32 in gemm1 epilogue): 256B rows,
// 1 dword gather/edge (same issue count as R14, avoids R15's double-issue
// failure). Predict spmm256 55.8->~35us, FETCH ->~90MB, absmax 0.5->~2-4
// (accuracy is the experiment's gate; x/spmm128 left bf16 to isolate it).
// ---------------------------------------------------------------------------

typedef short v8s __attribute__((ext_vector_type(8)));
typedef float v4f __attribute__((ext_vector_type(4)));
typedef float v2f __attribute__((ext_vector_type(2)));

__device__ inline unsigned bf16u(float f) {           // fp32 -> bf16 bits (RNE)
    unsigned u = __builtin_bit_cast(unsigned, f);
    return (u + 0x7fffu + ((u >> 16) & 1u)) >> 16;
}
__device__ inline float bflo(unsigned v) { return __builtin_bit_cast(float, v << 16); }
__device__ inline float bfhi(unsigned v) { return __builtin_bit_cast(float, v & 0xffff0000u); }

// ------------------- fused prep: x->bf16, degree hist, W^T -------------------
__global__ __launch_bounds__(256) void prep(
    const float* __restrict__ x, ushort* __restrict__ xh,
    const int* __restrict__ dst, int* __restrict__ deg,
    const float* __restrict__ W1, ushort* __restrict__ Wt1,
    const float* __restrict__ W2, ushort* __restrict__ Wt2, int E)
{
    int b = blockIdx.x;
    int t = threadIdx.x;
    if (b < 6250) {
        int i = b * 256 + t;                 // n4 = 1600000
        if (i < 1600000) {
            float4 v = ((const float4*)x)[i];
            unsigned lo = (bf16u(v.y) << 16) | bf16u(v.x);
            unsigned hi = (bf16u(v.w) << 16) | bf16u(v.z);
            ((uint2*)xh)[i] = make_uint2(lo, hi);
        }
    } else if (b < 9375) {
        int e = (b - 6250) * 256 + t;
        if (e < E) atomicAdd(&deg[dst[e]], 1);
    } else if (b < 9631) {
        int n = b - 9375;
        if (t < 128) Wt1[n * 128 + t] = (ushort)bf16u(W1[t * 256 + n]);
    } else {
        int n = b - 9631;
        Wt2[n * 256 + t] = (ushort)bf16u(W2[t * 256 + n]);
    }
}

// -------------- fused scan: local scan + decoupled lookback -----------------
__global__ __launch_bounds__(256) void scan_fused_k(
    const int* __restrict__ deg, int* __restrict__ off,
    int* __restrict__ cursor, int* __restrict__ bsum, int n, int E)
{
    __shared__ int s[256];
    __shared__ int psum[4];
    __shared__ int sboff;
    int tid = threadIdx.x;
    int b = blockIdx.x;
    int gid = b * 256 + tid;
    int v = (gid < n) ? deg[gid] : 0;
    s[tid] = v;
    __syncthreads();
    for (int o = 1; o < 256; o <<= 1) {
        int t = (tid >= o) ? s[tid - o] : 0;
        __syncthreads();
        s[tid] += t;
        __syncthreads();
    }
    int excl = s[tid] - v;
    int total = s[255];

    if (tid == 0) atomicExch(&bsum[b], total + 1);   // publish (sentinel +1)

    int pred = 0;
    if (tid < b) {
        int val;
        do { val = atomicAdd(&bsum[tid], 0); } while (val == 0);
        pred = val - 1;
    }
    #pragma unroll
    for (int o2 = 32; o2 > 0; o2 >>= 1) pred += __shfl_down(pred, o2, 64);
    if ((tid & 63) == 0) psum[tid >> 6] = pred;
    __syncthreads();
    if (tid == 0) sboff = psum[0] + psum[1] + psum[2] + psum[3];
    __syncthreads();

    if (gid < n) {
        int w = excl + sboff;
        off[gid] = w;
        cursor[gid] = w;
    }
    if (gid == 0) off[n] = E;
}

// packed edge: low 16 = src (N < 2^16), high 16 = bf16(weight).
// also zeroes g[128*256] (needed before gemm_pool's atomics, much later)
__global__ __launch_bounds__(256) void csr_fill(
    const int* __restrict__ src, const int* __restrict__ dst,
    const float* __restrict__ w, int* __restrict__ cursor,
    unsigned* __restrict__ edges, float* __restrict__ g, int E)
{
    int b = blockIdx.x, t = threadIdx.x;
    if (b < 128) g[b * 256 + t] = 0.f;
    int e = b * 256 + t;
    if (e >= E) return;
    int d = dst[e];
    int p = atomicAdd(&cursor[d], 1);
    edges[p] = (unsigned)src[e] | (bf16u(w[e]) << 16);
}

// ----------------------- gather SpMM (bf16 in/out) --------------------------
__global__ __launch_bounds__(256) void spmm128(
    const ushort* __restrict__ xh, const int* __restrict__ off,
    const unsigned* __restrict__ edges, ushort* __restrict__ S, int n)
{
    int node = blockIdx.x * 4 + (threadIdx.x >> 6);
    if (node >= n) return;
    int lane = threadIdx.x & 63;
    const unsigned* base = (const unsigned*)xh;   // row stride 64 uints
    int e0 = off[node], e1 = off[node + 1];
    float a0 = 0.f, a1 = 0.f;
    int e = e0;
    for (; e + 4 <= e1; e += 4) {
        unsigned ed0 = edges[e],     ed1 = edges[e + 1];
        unsigned ed2 = edges[e + 2], ed3 = edges[e + 3];
        float w0 = bfhi(ed0), w1 = bfhi(ed1);
        float w2 = bfhi(ed2), w3 = bfhi(ed3);
        unsigned v0 = base[(size_t)(ed0 & 0xffffu) * 64 + lane];
        unsigned v1 = base[(size_t)(ed1 & 0xffffu) * 64 + lane];
        unsigned v2 = base[(size_t)(ed2 & 0xffffu) * 64 + lane];
        unsigned v3 = base[(size_t)(ed3 & 0xffffu) * 64 + lane];
        a0 += bflo(v0) * w0 + bflo(v1) * w1 + bflo(v2) * w2 + bflo(v3) * w3;
        a1 += bfhi(v0) * w0 + bfhi(v1) * w1 + bfhi(v2) * w2 + bfhi(v3) * w3;
    }
    for (; e < e1; e++) {
        unsigned ed = edges[e];
        float w0 = bfhi(ed);
        unsigned v0 = base[(size_t)(ed & 0xffffu) * 64 + lane];
        a0 += bflo(v0) * w0;
        a1 += bfhi(v0) * w0;
    }
    ((unsigned*)S)[(size_t)node * 64 + lane] = (bf16u(a1) << 16) | bf16u(a0);
}

// --------------- gather SpMM layer 2: fp8 e4m3 in, bf16 out -----------------
// h8 rows are 256B (256 x fp8); one dword gather per edge per lane, hw
// v_cvt_pk_f32_fp8 unpacks 4 features. Same issue count as the bf16 R14
// loop, half the fetch bytes.
__global__ __launch_bounds__(256) void spmm256(
    const unsigned char* __restrict__ h8, const int* __restrict__ off,
    const unsigned* __restrict__ edges, ushort* __restrict__ S, int n)
{
    int node = blockIdx.x * 4 + (threadIdx.x >> 6);
    if (node >= n) return;
    int lane = threadIdx.x & 63;
    const unsigned* base = (const unsigned*)h8;    // row stride 64 uints (256B)
    int e0 = off[node], e1 = off[node + 1];
    float a0 = 0.f, a1 = 0.f, a2 = 0.f, a3 = 0.f;
    int e = e0;
    for (; e + 4 <= e1; e += 4) {
        unsigned ed0 = edges[e],     ed1 = edges[e + 1];
        unsigned ed2 = edges[e + 2], ed3 = edges[e + 3];
        float w0 = bfhi(ed0), w1 = bfhi(ed1);
        float w2 = bfhi(ed2), w3 = bfhi(ed3);
        unsigned v0 = base[(size_t)(ed0 & 0xffffu) * 64 + lane];
        unsigned v1 = base[(size_t)(ed1 & 0xffffu) * 64 + lane];
        unsigned v2 = base[(size_t)(ed2 & 0xffffu) * 64 + lane];
        unsigned v3 = base[(size_t)(ed3 & 0xffffu) * 64 + lane];
        v2f l0 = __builtin_amdgcn_cvt_pk_f32_fp8((int)v0, false);
        v2f h0 = __builtin_amdgcn_cvt_pk_f32_fp8((int)v0, true);
        v2f l1 = __builtin_amdgcn_cvt_pk_f32_fp8((int)v1, false);
        v2f h1v = __builtin_amdgcn_cvt_pk_f32_fp8((int)v1, true);
        v2f l2 = __builtin_amdgcn_cvt_pk_f32_fp8((int)v2, false);
        v2f h2 = __builtin_amdgcn_cvt_pk_f32_fp8((int)v2, true);
        v2f l3 = __builtin_amdgcn_cvt_pk_f32_fp8((int)v3, false);
        v2f h3 = __builtin_amdgcn_cvt_pk_f32_fp8((int)v3, true);
        a0 += l0.x * w0 + l1.x * w1 + l2.x * w2 + l3.x * w3;
        a1 += l0.y * w0 + l1.y * w1 + l2.y * w2 + l3.y * w3;
        a2 += h0.x * w0 + h1v.x * w1 + h2.x * w2 + h3.x * w3;
        a3 += h0.y * w0 + h1v.y * w1 + h2.y * w2 + h3.y * w3;
    }
    for (; e < e1; e++) {
        unsigned ed = edges[e];
        float w0 = bfhi(ed);
        unsigned v0 = base[(size_t)(ed & 0xffffu) * 64 + lane];
        v2f l0 = __builtin_amdgcn_cvt_pk_f32_fp8((int)v0, false);
        v2f h0 = __builtin_amdgcn_cvt_pk_f32_fp8((int)v0, true);
        a0 += l0.x * w0;
        a1 += l0.y * w0;
        a2 += h0.x * w0;
        a3 += h0.y * w0;
    }
    uint2 o;
    o.x = (bf16u(a1) << 16) | bf16u(a0);
    o.y = (bf16u(a3) << 16) | bf16u(a2);
    ((uint2*)S)[(size_t)node * 64 + lane] = o;
}

// ----------------- LDS-tiled MFMA bf16 GEMM, 128x256 tile -------------------
// 512 threads = 8 waves (2 row-halves x 4 col-quarters), BK=32.
// OFMT: 0=f32, 1=bf16, 2=fp8 e4m3. POOL=true: segment-pool into g via atomics.
template <int K, int OFMT, bool POOL>
__global__ __launch_bounds__(512) void gemm_tile(
    const ushort* __restrict__ A, const ushort* __restrict__ Wt,
    const float* __restrict__ bias, void* __restrict__ out,
    const int* __restrict__ seg, float* __restrict__ g, int M)
{
    __shared__ __align__(16) ushort As[128 * 32];   // 8 KB
    __shared__ __align__(16) ushort Bs[256 * 32];   // 16 KB
    __shared__ int segsh[128];

    const int tid = threadIdx.x;
    const int bm = blockIdx.x * 128;
    const int wave = tid >> 6, lane = tid & 63;
    const int wm = wave >> 2, wn = wave & 3;
    const int r = lane & 15, q = lane >> 4;

    if (POOL && tid < 128) {
        int gr = bm + tid;
        segsh[tid] = (gr < M) ? seg[gr] : 0x7fffffff;   // sentinel
    }

    const int o0 = tid * 16;           // 0..8191
    const int row0 = o0 >> 6;          // 0..127
    const int kb0 = o0 & 63;

    const char* Ab = (const char*)A;
    const char* Bb = (const char*)Wt;

    uint4 ra0, rb0, rb1;
    ra0 = *(const uint4*)(Ab + ((size_t)(bm + row0) * K) * 2 + kb0);
    rb0 = *(const uint4*)(Bb + ((size_t)(row0)       * K) * 2 + kb0);
    rb1 = *(const uint4*)(Bb + ((size_t)(row0 + 128) * K) * 2 + kb0);

    v4f acc[4][4];
    #pragma unroll
    for (int i = 0; i < 4; i++)
        #pragma unroll
        for (int j = 0; j < 4; j++) acc[i][j] = (v4f){0.f, 0.f, 0.f, 0.f};

    const int NK = K / 32;
    for (int ks = 0; ks < NK; ks++) {
        __syncthreads();
        *(uint4*)((char*)As + o0)        = ra0;
        *(uint4*)((char*)Bs + o0)        = rb0;
        *(uint4*)((char*)Bs + o0 + 8192) = rb1;
        if (ks + 1 < NK) {
            const int kof = (ks + 1) * 64;
            ra0 = *(const uint4*)(Ab + ((size_t)(bm + row0) * K) * 2 + kof + kb0);
            rb0 = *(const uint4*)(Bb + ((size_t)(row0)       * K) * 2 + kof + kb0);
            rb1 = *(const uint4*)(Bb + ((size_t)(row0 + 128) * K) * 2 + kof + kb0);
        }
        __syncthreads();

        v8s af[4], bf[4];
        #pragma unroll
        for (int i = 0; i < 4; i++)
            af[i] = *(const v8s*)(As + (wm * 64 + i * 16 + r) * 32 + q * 8);
        #pragma unroll
        for (int j = 0; j < 4; j++)
            bf[j] = *(const v8s*)(Bs + (wn * 64 + j * 16 + r) * 32 + q * 8);
        #pragma unroll
        for (int i = 0; i < 4; i++)
            #pragma unroll
            for (int j = 0; j < 4; j++)
                acc[i][j] = __builtin_amdgcn_mfma_f32_16x16x32_bf16(
                    af[i], bf[j], acc[i][j], 0, 0, 0);
    }

    if constexpr (POOL) {
        #pragma unroll
        for (int j = 0; j < 4; j++) {
            float b = bias[wn * 64 + j * 16 + r];
            #pragma unroll
            for (int i = 0; i < 4; i++)
                #pragma unroll
                for (int ii = 0; ii < 4; ii++)
                    acc[i][j][ii] = fmaxf(acc[i][j][ii] + b, 0.f);
        }
        int myseg[16];
        #pragma unroll
        for (int i = 0; i < 4; i++)
            #pragma unroll
            for (int ii = 0; ii < 4; ii++)
                myseg[i * 4 + ii] = segsh[wm * 64 + i * 16 + q * 4 + ii];
        int s_lo = segsh[0];
        int s_hi = segsh[min(127, M - 1 - bm)];
        for (int s = s_lo; s <= s_hi; s++) {
            #pragma unroll
            for (int j = 0; j < 4; j++) {
                float p = 0.f;
                #pragma unroll
                for (int i = 0; i < 4; i++)
                    #pragma unroll
                    for (int ii = 0; ii < 4; ii++)
                        if (myseg[i * 4 + ii] == s) p += acc[i][j][ii];
                p += __shfl_xor(p, 16, 64);
                p += __shfl_xor(p, 32, 64);
                if (lane < 16)
                    atomicAdd(&g[s * 256 + wn * 64 + j * 16 + r], p);
            }
        }
    } else {
        #pragma unroll
        for (int j = 0; j < 4; j++) {
            int col = wn * 64 + j * 16 + r;
            float b = bias[col];
            #pragma unroll
            for (int i = 0; i < 4; i++) {
                #pragma unroll
                for (int ii = 0; ii < 4; ii++) {
                    int row = bm + wm * 64 + i * 16 + q * 4 + ii;
                    if (row < M) {
                        float v = fmaxf(acc[i][j][ii] + b, 0.f);
                        if constexpr (OFMT == 1) {
                            ((ushort*)out)[(size_t)row * 256 + col] = (ushort)bf16u(v);
                        } else if constexpr (OFMT == 2) {
                            unsigned pk = (unsigned)__builtin_amdgcn_cvt_pk_fp8_f32(
                                v, v, 0, false);
                            ((unsigned char*)out)[(size_t)row * 256 + col] =
                                (unsigned char)(pk & 0xffu);
                        } else {
                            ((float*)out)[(size_t)row * 256 + col] = v;
                        }
                    }
                }
            }
        }
    }
}

// ---------------------------------- head ------------------------------------
__global__ __launch_bounds__(256) void head(
    const float* __restrict__ g, const float* __restrict__ Wd,
    const float* __restrict__ bd, const float* __restrict__ Wo,
    const float* __restrict__ bo, float* __restrict__ out)
{
    __shared__ float gr[256];
    int j = threadIdx.x;
    int gi = blockIdx.x;
    gr[j] = g[(size_t)gi * 256 + j];
    __syncthreads();
    float a2 = bd[j];
    for (int k = 0; k < 256; k++)
        a2 += gr[k] * Wd[(size_t)k * 256 + j];
    a2 = fmaxf(a2, 0.f);

    float v = a2 * Wo[j];
    #pragma unroll
    for (int off = 32; off > 0; off >>= 1)
        v += __shfl_down(v, off, 64);
    __shared__ float partial[4];
    if ((j & 63) == 0) partial[j >> 6] = v;
    __syncthreads();
    if (j == 0)
        out[gi] = partial[0] + partial[1] + partial[2] + partial[3] + bo[0];
}

extern "C" void kernel_launch(void* const* d_in, const int* in_sizes, int n_in,
                              void* d_out, int out_size, void* d_ws, size_t ws_size,
                              hipStream_t stream) {
    const float* x   = (const float*)d_in[0];
    const int*   esrc= (const int*)  d_in[1];
    const int*   edst= (const int*)  d_in[2];
    const float* ew  = (const float*)d_in[3];
    const int*   seg = (const int*)  d_in[4];
    const float* W1  = (const float*)d_in[5];
    const float* b1  = (const float*)d_in[6];
    const float* W2  = (const float*)d_in[7];
    const float* b2  = (const float*)d_in[8];
    const float* Wd  = (const float*)d_in[9];
    const float* bd  = (const float*)d_in[10];
    const float* Wo  = (const float*)d_in[11];
    const float* bo  = (const float*)d_in[12];
    float* out = (float*)d_out;

    const int N = 50000, E = 800000, G = 128, H = 256, F = 128;
    const int NPAD = 50048;            // 391 * 128
    const int NB = (N + 255) / 256;    // 196

    // workspace; region0 reused: {xh, S1}; deg+bsum contiguous (one memset)
    char* p = (char*)d_ws;
    char* region0 = p;                  p += (size_t)N * H * sizeof(float);    // 51.2 MB
    ushort* xh = (ushort*)region0;                                             // [N,128] bf16
    ushort* S1 = (ushort*)(region0 + (size_t)N * F * sizeof(ushort));          // [NPAD,128] bf16
    unsigned char* h8 = (unsigned char*)p;
                                        p += (size_t)N * H;                    // [N,256] fp8
    ushort* S2 = (ushort*)p;            p += (size_t)NPAD * H * sizeof(ushort);// [NPAD,256] bf16
    float* g   = (float*)p;             p += (size_t)G * H * sizeof(float);
    int*   deg = (int*)p;               p += (size_t)N * sizeof(int);
    int*   bsum= (int*)p;               p += 256 * sizeof(int);                // adjacent to deg
    int*   off = (int*)p;               p += (size_t)(N + 1) * sizeof(int) + 12;
    int*   cur = (int*)p;               p += (size_t)N * sizeof(int);
    unsigned* edges=(unsigned*)p;       p += (size_t)E * sizeof(unsigned);     // packed 4B (src,w)
    ushort* Wt1= (ushort*)p;            p += (size_t)H * F * sizeof(ushort);   // [256,128]
    ushort* Wt2= (ushort*)p;            p += (size_t)H * H * sizeof(ushort);   // [256,256]

    // ---- prep (x->bf16, deg hist, W^T) + CSR build ----
    hipMemsetAsync(deg, 0, ((size_t)N + 256) * sizeof(int), stream);  // deg + bsum
    prep<<<9887, 256, 0, stream>>>(x, xh, edst, deg, W1, Wt1, W2, Wt2, E);
    scan_fused_k<<<NB, 256, 0, stream>>>(deg, off, cur, bsum, N, E);
    csr_fill<<<(E + 255) / 256, 256, 0, stream>>>(esrc, edst, ew, cur, edges, g, E);

    // ---- layer 1: S1 = A@x ; h8 = fp8(relu(S1@W1 + b1)) ----
    spmm128<<<(N + 3) / 4, 256, 0, stream>>>(xh, off, edges, S1, N);
    gemm_tile<128, 2, false><<<NPAD / 128, 512, 0, stream>>>(
        S1, Wt1, b1, h8, nullptr, nullptr, N);

    // ---- layer 2: S2 = A@h8 ; pool(relu(S2@W2+b2)) fused into epilogue ----
    spmm256<<<(N + 3) / 4, 256, 0, stream>>>(h8, off, edges, S2, N);
    gemm_tile<256, 0, true><<<NPAD / 128, 512, 0, stream>>>(
        S2, Wt2, b2, nullptr, seg, g, N);

    // ---- head ----
    head<<<G, 256, 0, stream>>>(g, Wd, bd, Wo, bo, out);
}

// Round 2
// 283.620 us; speedup vs baseline: 1.1173x; 1.0732x over previous
//
#include <hip/hip_runtime.h>
#include <hip/hip_bf16.h>

// ---------------------------------------------------------------------------
// TwoLayerGCN. Round 18: binned CSR build replaces csr_fill.
// R17 counters: csr_fill WRITE_SIZE 53MB for 3.2MB payload = 16.6x = 64B/4B
// -> every scattered 4B edge write pays a full line writeback (16 writers of
// each line are random blocks on random XCDs; non-coherent L2s never merge).
// Fix: (1) bin_pass groups edges by 256-node bucket via LDS counting sort,
// writes coalesced runs of (packed,dst) into a stage buffer at bucket bases
// taken from off[]; (2) sort_pass: one block per bucket builds the final
// sorted edges[] segment entirely in LDS and streams it out coalesced --
// every output line has exactly one writer. No global cursor needed.
// Predict: csr_fill 55us -> bin+sort ~12us, build WRITE 53->14MB,
// total 304 -> ~265us, absmax unchanged.
// fp8 h1 path (R17, absmax 0.75) retained.
// ---------------------------------------------------------------------------

typedef short v8s __attribute__((ext_vector_type(8)));
typedef float v4f __attribute__((ext_vector_type(4)));
typedef float v2f __attribute__((ext_vector_type(2)));

__device__ inline unsigned bf16u(float f) {           // fp32 -> bf16 bits (RNE)
    unsigned u = __builtin_bit_cast(unsigned, f);
    return (u + 0x7fffu + ((u >> 16) & 1u)) >> 16;
}
__device__ inline float bflo(unsigned v) { return __builtin_bit_cast(float, v << 16); }
__device__ inline float bfhi(unsigned v) { return __builtin_bit_cast(float, v & 0xffff0000u); }

// ------------------- fused prep: x->bf16, degree hist, W^T -------------------
__global__ __launch_bounds__(256) void prep(
    const float* __restrict__ x, ushort* __restrict__ xh,
    const int* __restrict__ dst, int* __restrict__ deg,
    const float* __restrict__ W1, ushort* __restrict__ Wt1,
    const float* __restrict__ W2, ushort* __restrict__ Wt2, int E)
{
    int b = blockIdx.x;
    int t = threadIdx.x;
    if (b < 6250) {
        int i = b * 256 + t;                 // n4 = 1600000
        if (i < 1600000) {
            float4 v = ((const float4*)x)[i];
            unsigned lo = (bf16u(v.y) << 16) | bf16u(v.x);
            unsigned hi = (bf16u(v.w) << 16) | bf16u(v.z);
            ((uint2*)xh)[i] = make_uint2(lo, hi);
        }
    } else if (b < 9375) {
        int e = (b - 6250) * 256 + t;
        if (e < E) atomicAdd(&deg[dst[e]], 1);
    } else if (b < 9631) {
        int n = b - 9375;
        if (t < 128) Wt1[n * 128 + t] = (ushort)bf16u(W1[t * 256 + n]);
    } else {
        int n = b - 9631;
        Wt2[n * 256 + t] = (ushort)bf16u(W2[t * 256 + n]);
    }
}

// -------------- fused scan: local scan + decoupled lookback -----------------
// also initializes per-bucket stage cursors bcur[b] = off[b*256]
__global__ __launch_bounds__(256) void scan_fused_k(
    const int* __restrict__ deg, int* __restrict__ off,
    int* __restrict__ bcur, int* __restrict__ bsum, int n, int E)
{
    __shared__ int s[256];
    __shared__ int psum[4];
    __shared__ int sboff;
    int tid = threadIdx.x;
    int b = blockIdx.x;
    int gid = b * 256 + tid;
    int v = (gid < n) ? deg[gid] : 0;
    s[tid] = v;
    __syncthreads();
    for (int o = 1; o < 256; o <<= 1) {
        int t = (tid >= o) ? s[tid - o] : 0;
        __syncthreads();
        s[tid] += t;
        __syncthreads();
    }
    int excl = s[tid] - v;
    int total = s[255];

    if (tid == 0) atomicExch(&bsum[b], total + 1);   // publish (sentinel +1)

    int pred = 0;
    if (tid < b) {
        int val;
        do { val = atomicAdd(&bsum[tid], 0); } while (val == 0);
        pred = val - 1;
    }
    #pragma unroll
    for (int o2 = 32; o2 > 0; o2 >>= 1) pred += __shfl_down(pred, o2, 64);
    if ((tid & 63) == 0) psum[tid >> 6] = pred;
    __syncthreads();
    if (tid == 0) sboff = psum[0] + psum[1] + psum[2] + psum[3];
    __syncthreads();

    if (gid < n) {
        int w = excl + sboff;
        off[gid] = w;
        if ((gid & 255) == 0) bcur[gid >> 8] = w;   // bucket stage base
    }
    if (gid == 0) off[n] = E;
}

// --------------- pass A: bin edges by 256-node bucket (dst>>8) --------------
// Per block: 2048 edges. LDS counting-group by bucket, reserve a contiguous
// global run per bucket (one atomic each), write coalesced (packed,dst)
// runs into stage[]. Also zeroes g[128*256] for the pooling atomics.
__global__ __launch_bounds__(256) void bin_pass(
    const int* __restrict__ src, const int* __restrict__ dst,
    const float* __restrict__ w, int* __restrict__ bcur,
    uint2* __restrict__ stage, float* __restrict__ g, int E)
{
    __shared__ int hist[256];
    __shared__ int excl[256];
    __shared__ int gbase[256];
    __shared__ uint2 stg[2048];

    int t = threadIdx.x, b = blockIdx.x;
    if (b < 128) g[b * 256 + t] = 0.f;

    int e0 = b * 2048;
    hist[t] = 0;
    __syncthreads();

    int d_[8]; unsigned pk_[8]; int rk_[8]; int bk_[8];
    #pragma unroll
    for (int j = 0; j < 8; j++) {
        int e = e0 + t + j * 256;               // coalesced
        if (e < E) {
            int d = dst[e];
            d_[j] = d;
            bk_[j] = d >> 8;
            pk_[j] = (unsigned)src[e] | (bf16u(w[e]) << 16);
            rk_[j] = atomicAdd(&hist[bk_[j]], 1);
        } else d_[j] = -1;
    }
    __syncthreads();

    int cnt = hist[t];
    excl[t] = cnt;
    __syncthreads();
    for (int o = 1; o < 256; o <<= 1) {         // inclusive scan
        int v = (t >= o) ? excl[t - o] : 0;
        __syncthreads();
        excl[t] += v;
        __syncthreads();
    }
    int ex = excl[t] - cnt;                     // exclusive
    if (cnt > 0) gbase[t] = atomicAdd(&bcur[t], cnt);   // reserve run
    __syncthreads();
    excl[t] = ex;
    __syncthreads();

    #pragma unroll
    for (int j = 0; j < 8; j++)
        if (d_[j] >= 0)
            stg[excl[bk_[j]] + rk_[j]] = make_uint2(pk_[j], (unsigned)d_[j]);
    __syncthreads();

    int nval = min(2048, E - e0);
    #pragma unroll
    for (int j = 0; j < 8; j++) {
        int sidx = t + j * 256;                 // consecutive lanes -> consecutive gpos
        if (sidx < nval) {
            uint2 ent = stg[sidx];
            int bk = (int)(ent.y >> 8);
            stage[gbase[bk] + sidx - excl[bk]] = ent;
        }
    }
}

// --------------- pass B: per-bucket sort + coalesced edge write -------------
// One block per bucket. Reads the bucket's stage run (coalesced), ranks into
// a fully sorted LDS image using off[] (no global atomics), streams edges[]
// out linearly -> each output line has exactly one writer block.
__global__ __launch_bounds__(256) void sort_pass(
    const uint2* __restrict__ stage, const int* __restrict__ off,
    unsigned* __restrict__ edges, int N)
{
    __shared__ unsigned sorted[8192];           // 32 KB; bucket size ~4096+-64
    __shared__ int offL[257];
    __shared__ int hist[256];

    int t = threadIdx.x, b = blockIdx.x;
    int n0 = b * 256;
    offL[t] = off[min(n0 + t, N)];
    if (t == 0) offL[256] = off[min(n0 + 256, N)];
    hist[t] = 0;
    __syncthreads();

    int base = offL[0];
    int size = offL[256] - base;

    for (int i = t; i < size; i += 256) {
        uint2 ent = stage[base + i];
        int dl = (int)(ent.y & 255u);
        int r = atomicAdd(&hist[dl], 1);
        sorted[offL[dl] - base + r] = ent.x;
    }
    __syncthreads();
    for (int i = t; i < size; i += 256)
        edges[base + i] = sorted[i];
}

// ----------------------- gather SpMM (bf16 in/out) --------------------------
__global__ __launch_bounds__(256) void spmm128(
    const ushort* __restrict__ xh, const int* __restrict__ off,
    const unsigned* __restrict__ edges, ushort* __restrict__ S, int n)
{
    int node = blockIdx.x * 4 + (threadIdx.x >> 6);
    if (node >= n) return;
    int lane = threadIdx.x & 63;
    const unsigned* base = (const unsigned*)xh;   // row stride 64 uints
    int e0 = off[node], e1 = off[node + 1];
    float a0 = 0.f, a1 = 0.f;
    int e = e0;
    for (; e + 4 <= e1; e += 4) {
        unsigned ed0 = edges[e],     ed1 = edges[e + 1];
        unsigned ed2 = edges[e + 2], ed3 = edges[e + 3];
        float w0 = bfhi(ed0), w1 = bfhi(ed1);
        float w2 = bfhi(ed2), w3 = bfhi(ed3);
        unsigned v0 = base[(size_t)(ed0 & 0xffffu) * 64 + lane];
        unsigned v1 = base[(size_t)(ed1 & 0xffffu) * 64 + lane];
        unsigned v2 = base[(size_t)(ed2 & 0xffffu) * 64 + lane];
        unsigned v3 = base[(size_t)(ed3 & 0xffffu) * 64 + lane];
        a0 += bflo(v0) * w0 + bflo(v1) * w1 + bflo(v2) * w2 + bflo(v3) * w3;
        a1 += bfhi(v0) * w0 + bfhi(v1) * w1 + bfhi(v2) * w2 + bfhi(v3) * w3;
    }
    for (; e < e1; e++) {
        unsigned ed = edges[e];
        float w0 = bfhi(ed);
        unsigned v0 = base[(size_t)(ed & 0xffffu) * 64 + lane];
        a0 += bflo(v0) * w0;
        a1 += bfhi(v0) * w0;
    }
    ((unsigned*)S)[(size_t)node * 64 + lane] = (bf16u(a1) << 16) | bf16u(a0);
}

// --------------- gather SpMM layer 2: fp8 e4m3 in, bf16 out -----------------
__global__ __launch_bounds__(256) void spmm256(
    const unsigned char* __restrict__ h8, const int* __restrict__ off,
    const unsigned* __restrict__ edges, ushort* __restrict__ S, int n)
{
    int node = blockIdx.x * 4 + (threadIdx.x >> 6);
    if (node >= n) return;
    int lane = threadIdx.x & 63;
    const unsigned* base = (const unsigned*)h8;    // row stride 64 uints (256B)
    int e0 = off[node], e1 = off[node + 1];
    float a0 = 0.f, a1 = 0.f, a2 = 0.f, a3 = 0.f;
    int e = e0;
    for (; e + 4 <= e1; e += 4) {
        unsigned ed0 = edges[e],     ed1 = edges[e + 1];
        unsigned ed2 = edges[e + 2], ed3 = edges[e + 3];
        float w0 = bfhi(ed0), w1 = bfhi(ed1);
        float w2 = bfhi(ed2), w3 = bfhi(ed3);
        unsigned v0 = base[(size_t)(ed0 & 0xffffu) * 64 + lane];
        unsigned v1 = base[(size_t)(ed1 & 0xffffu) * 64 + lane];
        unsigned v2 = base[(size_t)(ed2 & 0xffffu) * 64 + lane];
        unsigned v3 = base[(size_t)(ed3 & 0xffffu) * 64 + lane];
        v2f l0 = __builtin_amdgcn_cvt_pk_f32_fp8((int)v0, false);
        v2f h0 = __builtin_amdgcn_cvt_pk_f32_fp8((int)v0, true);
        v2f l1 = __builtin_amdgcn_cvt_pk_f32_fp8((int)v1, false);
        v2f h1v = __builtin_amdgcn_cvt_pk_f32_fp8((int)v1, true);
        v2f l2 = __builtin_amdgcn_cvt_pk_f32_fp8((int)v2, false);
        v2f h2 = __builtin_amdgcn_cvt_pk_f32_fp8((int)v2, true);
        v2f l3 = __builtin_amdgcn_cvt_pk_f32_fp8((int)v3, false);
        v2f h3 = __builtin_amdgcn_cvt_pk_f32_fp8((int)v3, true);
        a0 += l0.x * w0 + l1.x * w1 + l2.x * w2 + l3.x * w3;
        a1 += l0.y * w0 + l1.y * w1 + l2.y * w2 + l3.y * w3;
        a2 += h0.x * w0 + h1v.x * w1 + h2.x * w2 + h3.x * w3;
        a3 += h0.y * w0 + h1v.y * w1 + h2.y * w2 + h3.y * w3;
    }
    for (; e < e1; e++) {
        unsigned ed = edges[e];
        float w0 = bfhi(ed);
        unsigned v0 = base[(size_t)(ed & 0xffffu) * 64 + lane];
        v2f l0 = __builtin_amdgcn_cvt_pk_f32_fp8((int)v0, false);
        v2f h0 = __builtin_amdgcn_cvt_pk_f32_fp8((int)v0, true);
        a0 += l0.x * w0;
        a1 += l0.y * w0;
        a2 += h0.x * w0;
        a3 += h0.y * w0;
    }
    uint2 o;
    o.x = (bf16u(a1) << 16) | bf16u(a0);
    o.y = (bf16u(a3) << 16) | bf16u(a2);
    ((uint2*)S)[(size_t)node * 64 + lane] = o;
}

// ----------------- LDS-tiled MFMA bf16 GEMM, 128x256 tile -------------------
// 512 threads = 8 waves (2 row-halves x 4 col-quarters), BK=32.
// OFMT: 0=f32, 1=bf16, 2=fp8 e4m3. POOL=true: segment-pool into g via atomics.
template <int K, int OFMT, bool POOL>
__global__ __launch_bounds__(512) void gemm_tile(
    const ushort* __restrict__ A, const ushort* __restrict__ Wt,
    const float* __restrict__ bias, void* __restrict__ out,
    const int* __restrict__ seg, float* __restrict__ g, int M)
{
    __shared__ __align__(16) ushort As[128 * 32];   // 8 KB
    __shared__ __align__(16) ushort Bs[256 * 32];   // 16 KB
    __shared__ int segsh[128];

    const int tid = threadIdx.x;
    const int bm = blockIdx.x * 128;
    const int wave = tid >> 6, lane = tid & 63;
    const int wm = wave >> 2, wn = wave & 3;
    const int r = lane & 15, q = lane >> 4;

    if (POOL && tid < 128) {
        int gr = bm + tid;
        segsh[tid] = (gr < M) ? seg[gr] : 0x7fffffff;   // sentinel
    }

    const int o0 = tid * 16;           // 0..8191
    const int row0 = o0 >> 6;          // 0..127
    const int kb0 = o0 & 63;

    const char* Ab = (const char*)A;
    const char* Bb = (const char*)Wt;

    uint4 ra0, rb0, rb1;
    ra0 = *(const uint4*)(Ab + ((size_t)(bm + row0) * K) * 2 + kb0);
    rb0 = *(const uint4*)(Bb + ((size_t)(row0)       * K) * 2 + kb0);
    rb1 = *(const uint4*)(Bb + ((size_t)(row0 + 128) * K) * 2 + kb0);

    v4f acc[4][4];
    #pragma unroll
    for (int i = 0; i < 4; i++)
        #pragma unroll
        for (int j = 0; j < 4; j++) acc[i][j] = (v4f){0.f, 0.f, 0.f, 0.f};

    const int NK = K / 32;
    for (int ks = 0; ks < NK; ks++) {
        __syncthreads();
        *(uint4*)((char*)As + o0)        = ra0;
        *(uint4*)((char*)Bs + o0)        = rb0;
        *(uint4*)((char*)Bs + o0 + 8192) = rb1;
        if (ks + 1 < NK) {
            const int kof = (ks + 1) * 64;
            ra0 = *(const uint4*)(Ab + ((size_t)(bm + row0) * K) * 2 + kof + kb0);
            rb0 = *(const uint4*)(Bb + ((size_t)(row0)       * K) * 2 + kof + kb0);
            rb1 = *(const uint4*)(Bb + ((size_t)(row0 + 128) * K) * 2 + kof + kb0);
        }
        __syncthreads();

        v8s af[4], bf[4];
        #pragma unroll
        for (int i = 0; i < 4; i++)
            af[i] = *(const v8s*)(As + (wm * 64 + i * 16 + r) * 32 + q * 8);
        #pragma unroll
        for (int j = 0; j < 4; j++)
            bf[j] = *(const v8s*)(Bs + (wn * 64 + j * 16 + r) * 32 + q * 8);
        #pragma unroll
        for (int i = 0; i < 4; i++)
            #pragma unroll
            for (int j = 0; j < 4; j++)
                acc[i][j] = __builtin_amdgcn_mfma_f32_16x16x32_bf16(
                    af[i], bf[j], acc[i][j], 0, 0, 0);
    }

    if constexpr (POOL) {
        #pragma unroll
        for (int j = 0; j < 4; j++) {
            float b = bias[wn * 64 + j * 16 + r];
            #pragma unroll
            for (int i = 0; i < 4; i++)
                #pragma unroll
                for (int ii = 0; ii < 4; ii++)
                    acc[i][j][ii] = fmaxf(acc[i][j][ii] + b, 0.f);
        }
        int myseg[16];
        #pragma unroll
        for (int i = 0; i < 4; i++)
            #pragma unroll
            for (int ii = 0; ii < 4; ii++)
                myseg[i * 4 + ii] = segsh[wm * 64 + i * 16 + q * 4 + ii];
        int s_lo = segsh[0];
        int s_hi = segsh[min(127, M - 1 - bm)];
        for (int s = s_lo; s <= s_hi; s++) {
            #pragma unroll
            for (int j = 0; j < 4; j++) {
                float p = 0.f;
                #pragma unroll
                for (int i = 0; i < 4; i++)
                    #pragma unroll
                    for (int ii = 0; ii < 4; ii++)
                        if (myseg[i * 4 + ii] == s) p += acc[i][j][ii];
                p += __shfl_xor(p, 16, 64);
                p += __shfl_xor(p, 32, 64);
                if (lane < 16)
                    atomicAdd(&g[s * 256 + wn * 64 + j * 16 + r], p);
            }
        }
    } else {
        #pragma unroll
        for (int j = 0; j < 4; j++) {
            int col = wn * 64 + j * 16 + r;
            float b = bias[col];
            #pragma unroll
            for (int i = 0; i < 4; i++) {
                #pragma unroll
                for (int ii = 0; ii < 4; ii++) {
                    int row = bm + wm * 64 + i * 16 + q * 4 + ii;
                    if (row < M) {
                        float v = fmaxf(acc[i][j][ii] + b, 0.f);
                        if constexpr (OFMT == 1) {
                            ((ushort*)out)[(size_t)row * 256 + col] = (ushort)bf16u(v);
                        } else if constexpr (OFMT == 2) {
                            unsigned pk = (unsigned)__builtin_amdgcn_cvt_pk_fp8_f32(
                                v, v, 0, false);
                            ((unsigned char*)out)[(size_t)row * 256 + col] =
                                (unsigned char)(pk & 0xffu);
                        } else {
                            ((float*)out)[(size_t)row * 256 + col] = v;
                        }
                    }
                }
            }
        }
    }
}

// ---------------------------------- head ------------------------------------
__global__ __launch_bounds__(256) void head(
    const float* __restrict__ g, const float* __restrict__ Wd,
    const float* __restrict__ bd, const float* __restrict__ Wo,
    const float* __restrict__ bo, float* __restrict__ out)
{
    __shared__ float gr[256];
    int j = threadIdx.x;
    int gi = blockIdx.x;
    gr[j] = g[(size_t)gi * 256 + j];
    __syncthreads();
    float a2 = bd[j];
    for (int k = 0; k < 256; k++)
        a2 += gr[k] * Wd[(size_t)k * 256 + j];
    a2 = fmaxf(a2, 0.f);

    float v = a2 * Wo[j];
    #pragma unroll
    for (int off = 32; off > 0; off >>= 1)
        v += __shfl_down(v, off, 64);
    __shared__ float partial[4];
    if ((j & 63) == 0) partial[j >> 6] = v;
    __syncthreads();
    if (j == 0)
        out[gi] = partial[0] + partial[1] + partial[2] + partial[3] + bo[0];
}

extern "C" void kernel_launch(void* const* d_in, const int* in_sizes, int n_in,
                              void* d_out, int out_size, void* d_ws, size_t ws_size,
                              hipStream_t stream) {
    const float* x   = (const float*)d_in[0];
    const int*   esrc= (const int*)  d_in[1];
    const int*   edst= (const int*)  d_in[2];
    const float* ew  = (const float*)d_in[3];
    const int*   seg = (const int*)  d_in[4];
    const float* W1  = (const float*)d_in[5];
    const float* b1  = (const float*)d_in[6];
    const float* W2  = (const float*)d_in[7];
    const float* b2  = (const float*)d_in[8];
    const float* Wd  = (const float*)d_in[9];
    const float* bd  = (const float*)d_in[10];
    const float* Wo  = (const float*)d_in[11];
    const float* bo  = (const float*)d_in[12];
    float* out = (float*)d_out;

    const int N = 50000, E = 800000, G = 128, H = 256, F = 128;
    const int NPAD = 50048;            // 391 * 128
    const int NB = (N + 255) / 256;    // 196 (= bucket count)

    // workspace; region0 reused: {xh, S1, stage}; deg+bsum contiguous
    char* p = (char*)d_ws;
    char* region0 = p;                  p += (size_t)N * H * sizeof(float);    // 51.2 MB
    ushort* xh = (ushort*)region0;                                             // [N,128] bf16
    ushort* S1 = (ushort*)(region0 + (size_t)N * F * sizeof(ushort));          // [NPAD,128] bf16
    uint2* stage = (uint2*)(region0 + (size_t)32 * 1024 * 1024);               // [E] 8B, dies pre-spmm128
    unsigned char* h8 = (unsigned char*)p;
                                        p += (size_t)N * H;                    // [N,256] fp8
    ushort* S2 = (ushort*)p;            p += (size_t)NPAD * H * sizeof(ushort);// [NPAD,256] bf16
    float* g   = (float*)p;             p += (size_t)G * H * sizeof(float);
    int*   deg = (int*)p;               p += (size_t)N * sizeof(int);
    int*   bsum= (int*)p;               p += 256 * sizeof(int);                // adjacent to deg
    int*   off = (int*)p;               p += (size_t)(N + 1) * sizeof(int) + 12;
    int*   bcur= (int*)p;               p += (size_t)N * sizeof(int);          // 196 used
    unsigned* edges=(unsigned*)p;       p += (size_t)E * sizeof(unsigned);     // packed 4B (src,w)
    ushort* Wt1= (ushort*)p;            p += (size_t)H * F * sizeof(ushort);   // [256,128]
    ushort* Wt2= (ushort*)p;            p += (size_t)H * H * sizeof(ushort);   // [256,256]

    // ---- prep (x->bf16, deg hist, W^T) + binned CSR build ----
    hipMemsetAsync(deg, 0, ((size_t)N + 256) * sizeof(int), stream);  // deg + bsum
    prep<<<9887, 256, 0, stream>>>(x, xh, edst, deg, W1, Wt1, W2, Wt2, E);
    scan_fused_k<<<NB, 256, 0, stream>>>(deg, off, bcur, bsum, N, E);
    bin_pass<<<(E + 2047) / 2048, 256, 0, stream>>>(esrc, edst, ew, bcur, stage, g, E);
    sort_pass<<<NB, 256, 0, stream>>>(stage, off, edges, N);

    // ---- layer 1: S1 = A@x ; h8 = fp8(relu(S1@W1 + b1)) ----
    spmm128<<<(N + 3) / 4, 256, 0, stream>>>(xh, off, edges, S1, N);
    gemm_tile<128, 2, false><<<NPAD / 128, 512, 0, stream>>>(
        S1, Wt1, b1, h8, nullptr, nullptr, N);

    // ---- layer 2: S2 = A@h8 ; pool(relu(S2@W2+b2)) fused into epilogue ----
    spmm256<<<(N + 3) / 4, 256, 0, stream>>>(h8, off, edges, S2, N);
    gemm_tile<256, 0, true><<<NPAD / 128, 512, 0, stream>>>(
        S2, Wt2, b2, nullptr, seg, g, N);

    // ---- head ----
    head<<<G, 256, 0, stream>>>(g, Wd, bd, Wo, bo, out);
}

// Round 3
// 243.858 us; speedup vs baseline: 1.2995x; 1.1631x over previous
//
#include <hip/hip_runtime.h>
#include <hip/hip_bf16.h>

// ---------------------------------------------------------------------------
// TwoLayerGCN. Round 19: kill the degree-histogram atomics + fuse scan.
// R18 counters: prep 43us @ VALUBusy 1.7%, WRITE 37.6MB vs 13.2MB payload ->
// the 800k random device-scope atomicAdd(&deg[dst]) dominate (random-line RMW
// ~20G/s ~= 40us + ~24MB write amp). The binning pass already counts edges,
// so deg/scan are redundant: bin_pass now stages into fixed-capacity bucket
// regions (6144/bucket = mean+32sigma) reserved off 196 L2-hot counters;
// sort_build derives the per-node histogram in LDS from the staged bucket,
// scans it, writes off[] directly (bucket base = 196-count reduce), ranks
// a sorted LDS image, streams edges coalesced. Deletes: prep's atomic branch,
// deg[], scan_fused_k, the 200KB memset. Predict prep 43->~8us (WRITE
// ->13MB), scan gone, total 283.6 -> ~240us, absmax ~unchanged.
// fp8 h1 (R17) + binned coalesced build (R18) retained.
// ---------------------------------------------------------------------------

typedef short v8s __attribute__((ext_vector_type(8)));
typedef float v4f __attribute__((ext_vector_type(4)));
typedef float v2f __attribute__((ext_vector_type(2)));

#define BKT_CAP 6144   // stage capacity per 256-node bucket (mean 4096, std 64)

__device__ inline unsigned bf16u(float f) {           // fp32 -> bf16 bits (RNE)
    unsigned u = __builtin_bit_cast(unsigned, f);
    return (u + 0x7fffu + ((u >> 16) & 1u)) >> 16;
}
__device__ inline float bflo(unsigned v) { return __builtin_bit_cast(float, v << 16); }
__device__ inline float bfhi(unsigned v) { return __builtin_bit_cast(float, v & 0xffff0000u); }

// ---------------------- fused prep: x->bf16, W^T ----------------------------
__global__ __launch_bounds__(256) void prep(
    const float* __restrict__ x, ushort* __restrict__ xh,
    const float* __restrict__ W1, ushort* __restrict__ Wt1,
    const float* __restrict__ W2, ushort* __restrict__ Wt2)
{
    int b = blockIdx.x;
    int t = threadIdx.x;
    if (b < 6250) {
        int i = b * 256 + t;                 // n4 = 1600000
        if (i < 1600000) {
            float4 v = ((const float4*)x)[i];
            unsigned lo = (bf16u(v.y) << 16) | bf16u(v.x);
            unsigned hi = (bf16u(v.w) << 16) | bf16u(v.z);
            ((uint2*)xh)[i] = make_uint2(lo, hi);
        }
    } else if (b < 6506) {
        int n = b - 6250;
        if (t < 128) Wt1[n * 128 + t] = (ushort)bf16u(W1[t * 256 + n]);
    } else {
        int n = b - 6506;
        Wt2[n * 256 + t] = (ushort)bf16u(W2[t * 256 + n]);
    }
}

// --------------- pass A: bin edges by 256-node bucket (dst>>8) --------------
// Per block: 2048 edges. LDS counting-group by bucket, reserve a run in the
// bucket's fixed-capacity stage region (one atomic per touched bucket on a
// 196-counter L2-hot array), write coalesced (packed,dst) runs.
// Also zeroes g[128*256] for the pooling atomics much later.
__global__ __launch_bounds__(256) void bin_pass(
    const int* __restrict__ src, const int* __restrict__ dst,
    const float* __restrict__ w, int* __restrict__ bcnt,
    uint2* __restrict__ stage, float* __restrict__ g, int E)
{
    __shared__ int hist[256];
    __shared__ int excl[256];
    __shared__ int gbase[256];
    __shared__ uint2 stg[2048];

    int t = threadIdx.x, b = blockIdx.x;
    if (b < 128) g[b * 256 + t] = 0.f;

    int e0 = b * 2048;
    hist[t] = 0;
    __syncthreads();

    int d_[8]; unsigned pk_[8]; int rk_[8]; int bk_[8];
    #pragma unroll
    for (int j = 0; j < 8; j++) {
        int e = e0 + t + j * 256;               // coalesced
        if (e < E) {
            int d = dst[e];
            d_[j] = d;
            bk_[j] = d >> 8;
            pk_[j] = (unsigned)src[e] | (bf16u(w[e]) << 16);
            rk_[j] = atomicAdd(&hist[bk_[j]], 1);
        } else d_[j] = -1;
    }
    __syncthreads();

    int cnt = hist[t];
    excl[t] = cnt;
    __syncthreads();
    for (int o = 1; o < 256; o <<= 1) {         // inclusive scan
        int v = (t >= o) ? excl[t - o] : 0;
        __syncthreads();
        excl[t] += v;
        __syncthreads();
    }
    int ex = excl[t] - cnt;                     // exclusive
    if (cnt > 0) gbase[t] = atomicAdd(&bcnt[t], cnt);   // reserve run
    __syncthreads();
    excl[t] = ex;
    __syncthreads();

    #pragma unroll
    for (int j = 0; j < 8; j++)
        if (d_[j] >= 0)
            stg[excl[bk_[j]] + rk_[j]] = make_uint2(pk_[j], (unsigned)d_[j]);
    __syncthreads();

    int nval = min(2048, E - e0);
    #pragma unroll
    for (int j = 0; j < 8; j++) {
        int sidx = t + j * 256;                 // consecutive lanes -> consecutive gpos
        if (sidx < nval) {
            uint2 ent = stg[sidx];
            int bk = (int)(ent.y >> 8);
            stage[(size_t)bk * BKT_CAP + gbase[bk] + sidx - excl[bk]] = ent;
        }
    }
}

// ------ pass B: per-bucket histogram + scan -> off[], sort -> edges[] -------
// One block per bucket. Bucket base = reduce over bcnt[0..b-1] (196 ints,
// L2-hot). LDS histogram of dst low byte gives per-node degrees -> off[]
// written directly (no global deg array, no global scan). Rank into a fully
// sorted LDS image, stream edges[] out linearly coalesced.
__global__ __launch_bounds__(256) void sort_build(
    const uint2* __restrict__ stage, const int* __restrict__ bcnt,
    unsigned* __restrict__ edges, int* __restrict__ off, int N, int E)
{
    __shared__ unsigned sorted[BKT_CAP];        // 24 KB
    __shared__ int hist[256];
    __shared__ int s[256];
    __shared__ int cur[256];
    __shared__ int psum[4];
    __shared__ int sbase;

    int t = threadIdx.x, b = blockIdx.x;
    const uint2* reg = stage + (size_t)b * BKT_CAP;
    int cnt = bcnt[b];

    // bucket base = sum of bcnt[0..b-1]
    int pred = (t < b) ? bcnt[t] : 0;
    #pragma unroll
    for (int o = 32; o > 0; o >>= 1) pred += __shfl_down(pred, o, 64);
    if ((t & 63) == 0) psum[t >> 6] = pred;
    hist[t] = 0;
    __syncthreads();
    if (t == 0) sbase = psum[0] + psum[1] + psum[2] + psum[3];

    for (int i = t; i < cnt; i += 256)
        atomicAdd(&hist[reg[i].y & 255u], 1);   // LDS atomic
    __syncthreads();

    int h = hist[t];
    s[t] = h;
    __syncthreads();
    for (int o = 1; o < 256; o <<= 1) {         // inclusive scan
        int v = (t >= o) ? s[t - o] : 0;
        __syncthreads();
        s[t] += v;
        __syncthreads();
    }
    int ex = s[t] - h;                          // exclusive
    cur[t] = ex;
    __syncthreads();

    int nn = b * 256 + t;
    if (nn <= N) off[nn] = sbase + ex;          // nn==N lands off[N]=E exactly

    for (int i = t; i < cnt; i += 256) {
        uint2 ent = reg[i];
        int r = atomicAdd(&cur[ent.y & 255u], 1);
        sorted[r] = ent.x;
    }
    __syncthreads();
    for (int i = t; i < cnt; i += 256)
        edges[sbase + i] = sorted[i];
}

// ----------------------- gather SpMM (bf16 in/out) --------------------------
__global__ __launch_bounds__(256) void spmm128(
    const ushort* __restrict__ xh, const int* __restrict__ off,
    const unsigned* __restrict__ edges, ushort* __restrict__ S, int n)
{
    int node = blockIdx.x * 4 + (threadIdx.x >> 6);
    if (node >= n) return;
    int lane = threadIdx.x & 63;
    const unsigned* base = (const unsigned*)xh;   // row stride 64 uints
    int e0 = off[node], e1 = off[node + 1];
    float a0 = 0.f, a1 = 0.f;
    int e = e0;
    for (; e + 4 <= e1; e += 4) {
        unsigned ed0 = edges[e],     ed1 = edges[e + 1];
        unsigned ed2 = edges[e + 2], ed3 = edges[e + 3];
        float w0 = bfhi(ed0), w1 = bfhi(ed1);
        float w2 = bfhi(ed2), w3 = bfhi(ed3);
        unsigned v0 = base[(size_t)(ed0 & 0xffffu) * 64 + lane];
        unsigned v1 = base[(size_t)(ed1 & 0xffffu) * 64 + lane];
        unsigned v2 = base[(size_t)(ed2 & 0xffffu) * 64 + lane];
        unsigned v3 = base[(size_t)(ed3 & 0xffffu) * 64 + lane];
        a0 += bflo(v0) * w0 + bflo(v1) * w1 + bflo(v2) * w2 + bflo(v3) * w3;
        a1 += bfhi(v0) * w0 + bfhi(v1) * w1 + bfhi(v2) * w2 + bfhi(v3) * w3;
    }
    for (; e < e1; e++) {
        unsigned ed = edges[e];
        float w0 = bfhi(ed);
        unsigned v0 = base[(size_t)(ed & 0xffffu) * 64 + lane];
        a0 += bflo(v0) * w0;
        a1 += bfhi(v0) * w0;
    }
    ((unsigned*)S)[(size_t)node * 64 + lane] = (bf16u(a1) << 16) | bf16u(a0);
}

// --------------- gather SpMM layer 2: fp8 e4m3 in, bf16 out -----------------
__global__ __launch_bounds__(256) void spmm256(
    const unsigned char* __restrict__ h8, const int* __restrict__ off,
    const unsigned* __restrict__ edges, ushort* __restrict__ S, int n)
{
    int node = blockIdx.x * 4 + (threadIdx.x >> 6);
    if (node >= n) return;
    int lane = threadIdx.x & 63;
    const unsigned* base = (const unsigned*)h8;    // row stride 64 uints (256B)
    int e0 = off[node], e1 = off[node + 1];
    float a0 = 0.f, a1 = 0.f, a2 = 0.f, a3 = 0.f;
    int e = e0;
    for (; e + 4 <= e1; e += 4) {
        unsigned ed0 = edges[e],     ed1 = edges[e + 1];
        unsigned ed2 = edges[e + 2], ed3 = edges[e + 3];
        float w0 = bfhi(ed0), w1 = bfhi(ed1);
        float w2 = bfhi(ed2), w3 = bfhi(ed3);
        unsigned v0 = base[(size_t)(ed0 & 0xffffu) * 64 + lane];
        unsigned v1 = base[(size_t)(ed1 & 0xffffu) * 64 + lane];
        unsigned v2 = base[(size_t)(ed2 & 0xffffu) * 64 + lane];
        unsigned v3 = base[(size_t)(ed3 & 0xffffu) * 64 + lane];
        v2f l0 = __builtin_amdgcn_cvt_pk_f32_fp8((int)v0, false);
        v2f h0 = __builtin_amdgcn_cvt_pk_f32_fp8((int)v0, true);
        v2f l1 = __builtin_amdgcn_cvt_pk_f32_fp8((int)v1, false);
        v2f h1v = __builtin_amdgcn_cvt_pk_f32_fp8((int)v1, true);
        v2f l2 = __builtin_amdgcn_cvt_pk_f32_fp8((int)v2, false);
        v2f h2 = __builtin_amdgcn_cvt_pk_f32_fp8((int)v2, true);
        v2f l3 = __builtin_amdgcn_cvt_pk_f32_fp8((int)v3, false);
        v2f h3 = __builtin_amdgcn_cvt_pk_f32_fp8((int)v3, true);
        a0 += l0.x * w0 + l1.x * w1 + l2.x * w2 + l3.x * w3;
        a1 += l0.y * w0 + l1.y * w1 + l2.y * w2 + l3.y * w3;
        a2 += h0.x * w0 + h1v.x * w1 + h2.x * w2 + h3.x * w3;
        a3 += h0.y * w0 + h1v.y * w1 + h2.y * w2 + h3.y * w3;
    }
    for (; e < e1; e++) {
        unsigned ed = edges[e];
        float w0 = bfhi(ed);
        unsigned v0 = base[(size_t)(ed & 0xffffu) * 64 + lane];
        v2f l0 = __builtin_amdgcn_cvt_pk_f32_fp8((int)v0, false);
        v2f h0 = __builtin_amdgcn_cvt_pk_f32_fp8((int)v0, true);
        a0 += l0.x * w0;
        a1 += l0.y * w0;
        a2 += h0.x * w0;
        a3 += h0.y * w0;
    }
    uint2 o;
    o.x = (bf16u(a1) << 16) | bf16u(a0);
    o.y = (bf16u(a3) << 16) | bf16u(a2);
    ((uint2*)S)[(size_t)node * 64 + lane] = o;
}

// ----------------- LDS-tiled MFMA bf16 GEMM, 128x256 tile -------------------
// 512 threads = 8 waves (2 row-halves x 4 col-quarters), BK=32.
// OFMT: 0=f32, 1=bf16, 2=fp8 e4m3. POOL=true: segment-pool into g via atomics.
template <int K, int OFMT, bool POOL>
__global__ __launch_bounds__(512) void gemm_tile(
    const ushort* __restrict__ A, const ushort* __restrict__ Wt,
    const float* __restrict__ bias, void* __restrict__ out,
    const int* __restrict__ seg, float* __restrict__ g, int M)
{
    __shared__ __align__(16) ushort As[128 * 32];   // 8 KB
    __shared__ __align__(16) ushort Bs[256 * 32];   // 16 KB
    __shared__ int segsh[128];

    const int tid = threadIdx.x;
    const int bm = blockIdx.x * 128;
    const int wave = tid >> 6, lane = tid & 63;
    const int wm = wave >> 2, wn = wave & 3;
    const int r = lane & 15, q = lane >> 4;

    if (POOL && tid < 128) {
        int gr = bm + tid;
        segsh[tid] = (gr < M) ? seg[gr] : 0x7fffffff;   // sentinel
    }

    const int o0 = tid * 16;           // 0..8191
    const int row0 = o0 >> 6;          // 0..127
    const int kb0 = o0 & 63;

    const char* Ab = (const char*)A;
    const char* Bb = (const char*)Wt;

    uint4 ra0, rb0, rb1;
    ra0 = *(const uint4*)(Ab + ((size_t)(bm + row0) * K) * 2 + kb0);
    rb0 = *(const uint4*)(Bb + ((size_t)(row0)       * K) * 2 + kb0);
    rb1 = *(const uint4*)(Bb + ((size_t)(row0 + 128) * K) * 2 + kb0);

    v4f acc[4][4];
    #pragma unroll
    for (int i = 0; i < 4; i++)
        #pragma unroll
        for (int j = 0; j < 4; j++) acc[i][j] = (v4f){0.f, 0.f, 0.f, 0.f};

    const int NK = K / 32;
    for (int ks = 0; ks < NK; ks++) {
        __syncthreads();
        *(uint4*)((char*)As + o0)        = ra0;
        *(uint4*)((char*)Bs + o0)        = rb0;
        *(uint4*)((char*)Bs + o0 + 8192) = rb1;
        if (ks + 1 < NK) {
            const int kof = (ks + 1) * 64;
            ra0 = *(const uint4*)(Ab + ((size_t)(bm + row0) * K) * 2 + kof + kb0);
            rb0 = *(const uint4*)(Bb + ((size_t)(row0)       * K) * 2 + kof + kb0);
            rb1 = *(const uint4*)(Bb + ((size_t)(row0 + 128) * K) * 2 + kof + kb0);
        }
        __syncthreads();

        v8s af[4], bf[4];
        #pragma unroll
        for (int i = 0; i < 4; i++)
            af[i] = *(const v8s*)(As + (wm * 64 + i * 16 + r) * 32 + q * 8);
        #pragma unroll
        for (int j = 0; j < 4; j++)
            bf[j] = *(const v8s*)(Bs + (wn * 64 + j * 16 + r) * 32 + q * 8);
        #pragma unroll
        for (int i = 0; i < 4; i++)
            #pragma unroll
            for (int j = 0; j < 4; j++)
                acc[i][j] = __builtin_amdgcn_mfma_f32_16x16x32_bf16(
                    af[i], bf[j], acc[i][j], 0, 0, 0);
    }

    if constexpr (POOL) {
        #pragma unroll
        for (int j = 0; j < 4; j++) {
            float b = bias[wn * 64 + j * 16 + r];
            #pragma unroll
            for (int i = 0; i < 4; i++)
                #pragma unroll
                for (int ii = 0; ii < 4; ii++)
                    acc[i][j][ii] = fmaxf(acc[i][j][ii] + b, 0.f);
        }
        int myseg[16];
        #pragma unroll
        for (int i = 0; i < 4; i++)
            #pragma unroll
            for (int ii = 0; ii < 4; ii++)
                myseg[i * 4 + ii] = segsh[wm * 64 + i * 16 + q * 4 + ii];
        int s_lo = segsh[0];
        int s_hi = segsh[min(127, M - 1 - bm)];
        for (int s = s_lo; s <= s_hi; s++) {
            #pragma unroll
            for (int j = 0; j < 4; j++) {
                float p = 0.f;
                #pragma unroll
                for (int i = 0; i < 4; i++)
                    #pragma unroll
                    for (int ii = 0; ii < 4; ii++)
                        if (myseg[i * 4 + ii] == s) p += acc[i][j][ii];
                p += __shfl_xor(p, 16, 64);
                p += __shfl_xor(p, 32, 64);
                if (lane < 16)
                    atomicAdd(&g[s * 256 + wn * 64 + j * 16 + r], p);
            }
        }
    } else {
        #pragma unroll
        for (int j = 0; j < 4; j++) {
            int col = wn * 64 + j * 16 + r;
            float b = bias[col];
            #pragma unroll
            for (int i = 0; i < 4; i++) {
                #pragma unroll
                for (int ii = 0; ii < 4; ii++) {
                    int row = bm + wm * 64 + i * 16 + q * 4 + ii;
                    if (row < M) {
                        float v = fmaxf(acc[i][j][ii] + b, 0.f);
                        if constexpr (OFMT == 1) {
                            ((ushort*)out)[(size_t)row * 256 + col] = (ushort)bf16u(v);
                        } else if constexpr (OFMT == 2) {
                            unsigned pk = (unsigned)__builtin_amdgcn_cvt_pk_fp8_f32(
                                v, v, 0, false);
                            ((unsigned char*)out)[(size_t)row * 256 + col] =
                                (unsigned char)(pk & 0xffu);
                        } else {
                            ((float*)out)[(size_t)row * 256 + col] = v;
                        }
                    }
                }
            }
        }
    }
}

// ---------------------------------- head ------------------------------------
__global__ __launch_bounds__(256) void head(
    const float* __restrict__ g, const float* __restrict__ Wd,
    const float* __restrict__ bd, const float* __restrict__ Wo,
    const float* __restrict__ bo, float* __restrict__ out)
{
    __shared__ float gr[256];
    int j = threadIdx.x;
    int gi = blockIdx.x;
    gr[j] = g[(size_t)gi * 256 + j];
    __syncthreads();
    float a2 = bd[j];
    for (int k = 0; k < 256; k++)
        a2 += gr[k] * Wd[(size_t)k * 256 + j];
    a2 = fmaxf(a2, 0.f);

    float v = a2 * Wo[j];
    #pragma unroll
    for (int off = 32; off > 0; off >>= 1)
        v += __shfl_down(v, off, 64);
    __shared__ float partial[4];
    if ((j & 63) == 0) partial[j >> 6] = v;
    __syncthreads();
    if (j == 0)
        out[gi] = partial[0] + partial[1] + partial[2] + partial[3] + bo[0];
}

extern "C" void kernel_launch(void* const* d_in, const int* in_sizes, int n_in,
                              void* d_out, int out_size, void* d_ws, size_t ws_size,
                              hipStream_t stream) {
    const float* x   = (const float*)d_in[0];
    const int*   esrc= (const int*)  d_in[1];
    const int*   edst= (const int*)  d_in[2];
    const float* ew  = (const float*)d_in[3];
    const int*   seg = (const int*)  d_in[4];
    const float* W1  = (const float*)d_in[5];
    const float* b1  = (const float*)d_in[6];
    const float* W2  = (const float*)d_in[7];
    const float* b2  = (const float*)d_in[8];
    const float* Wd  = (const float*)d_in[9];
    const float* bd  = (const float*)d_in[10];
    const float* Wo  = (const float*)d_in[11];
    const float* bo  = (const float*)d_in[12];
    float* out = (float*)d_out;

    const int N = 50000, E = 800000, G = 128, H = 256, F = 128;
    const int NPAD = 50048;            // 391 * 128
    const int NB = (N + 255) / 256;    // 196 (= bucket count)

    // workspace; region0 reused: {xh, S1, stage}; stage dies before spmm128
    char* p = (char*)d_ws;
    char* region0 = p;                  p += (size_t)N * H * sizeof(float);    // 51.2 MB
    ushort* xh = (ushort*)region0;                                             // [N,128] bf16
    ushort* S1 = (ushort*)(region0 + (size_t)N * F * sizeof(ushort));          // [NPAD,128] bf16
    uint2* stage = (uint2*)(region0 + (size_t)32 * 1024 * 1024);               // 196*6144*8B = 9.6MB
    unsigned char* h8 = (unsigned char*)p;
                                        p += (size_t)N * H;                    // [N,256] fp8
    ushort* S2 = (ushort*)p;            p += (size_t)NPAD * H * sizeof(ushort);// [NPAD,256] bf16
    float* g   = (float*)p;             p += (size_t)G * H * sizeof(float);
    int*   bcnt= (int*)p;               p += 256 * sizeof(int);                // bucket counts
    int*   off = (int*)p;               p += (size_t)(N + 1) * sizeof(int) + 12;
    unsigned* edges=(unsigned*)p;       p += (size_t)E * sizeof(unsigned);     // packed 4B (src,w)
    ushort* Wt1= (ushort*)p;            p += (size_t)H * F * sizeof(ushort);   // [256,128]
    ushort* Wt2= (ushort*)p;            p += (size_t)H * H * sizeof(ushort);   // [256,256]

    // ---- prep (x->bf16, W^T) + binned CSR build (no deg, no global scan) ----
    hipMemsetAsync(bcnt, 0, 256 * sizeof(int), stream);
    prep<<<6762, 256, 0, stream>>>(x, xh, W1, Wt1, W2, Wt2);
    bin_pass<<<(E + 2047) / 2048, 256, 0, stream>>>(esrc, edst, ew, bcnt, stage, g, E);
    sort_build<<<NB, 256, 0, stream>>>(stage, bcnt, edges, off, N, E);

    // ---- layer 1: S1 = A@x ; h8 = fp8(relu(S1@W1 + b1)) ----
    spmm128<<<(N + 3) / 4, 256, 0, stream>>>(xh, off, edges, S1, N);
    gemm_tile<128, 2, false><<<NPAD / 128, 512, 0, stream>>>(
        S1, Wt1, b1, h8, nullptr, nullptr, N);

    // ---- layer 2: S2 = A@h8 ; pool(relu(S2@W2+b2)) fused into epilogue ----
    spmm256<<<(N + 3) / 4, 256, 0, stream>>>(h8, off, edges, S2, N);
    gemm_tile<256, 0, true><<<NPAD / 128, 512, 0, stream>>>(
        S2, Wt2, b2, nullptr, seg, g, N);

    // ---- head ----
    head<<<G, 256, 0, stream>>>(g, Wd, bd, Wo, bo, out);
}

// Round 4
// 240.441 us; speedup vs baseline: 1.3180x; 1.0142x over previous
//
#include <hip/hip_runtime.h>
#include <hip/hip_bf16.h>

// ---------------------------------------------------------------------------
// TwoLayerGCN. Round 20: fp8 x for the layer-1 gather.
// R19 matched (-40us): build path now ~21us total. Top-5 is the harness's
// 268MB workspace re-poison (fillBufferAligned, not ours). Largest own
// kernels: spmm256 ~32us (at fp8 compulsory-gather floor), spmm128 ~30us --
// still gathering 256B bf16 rows (compulsory 43250 x 256B x 8 XCD = 89MB).
// This round: x stored fp8 e4m3 (rows 128B = 64 lanes x ushort, 1 load/edge
// /lane as before, 2 fully-used lines). Compulsory fetch halves to 44MB.
// Accuracy precedent: R17's fp8-h1 moved absmax only 0.5->0.75 (sqrt-N noise
// cancellation through 16-edge sums + 256-dim contractions); predict
// absmax ~1.0-1.3, spmm128 ~30->18us, prep -2us, total 244->~228us.
// fp8 h1 (R17) + binned build (R18) + fused off[] derivation (R19) retained.
// ---------------------------------------------------------------------------

typedef short v8s __attribute__((ext_vector_type(8)));
typedef float v4f __attribute__((ext_vector_type(4)));
typedef float v2f __attribute__((ext_vector_type(2)));

#define BKT_CAP 6144   // stage capacity per 256-node bucket (mean 4096, std 64)

__device__ inline unsigned bf16u(float f) {           // fp32 -> bf16 bits (RNE)
    unsigned u = __builtin_bit_cast(unsigned, f);
    return (u + 0x7fffu + ((u >> 16) & 1u)) >> 16;
}
__device__ inline float bflo(unsigned v) { return __builtin_bit_cast(float, v << 16); }
__device__ inline float bfhi(unsigned v) { return __builtin_bit_cast(float, v & 0xffff0000u); }

// ---------------------- fused prep: x->fp8, W^T -----------------------------
__global__ __launch_bounds__(256) void prep(
    const float* __restrict__ x, unsigned char* __restrict__ x8,
    const float* __restrict__ W1, ushort* __restrict__ Wt1,
    const float* __restrict__ W2, ushort* __restrict__ Wt2)
{
    int b = blockIdx.x;
    int t = threadIdx.x;
    if (b < 6250) {
        int i = b * 256 + t;                 // n4 = 1600000
        if (i < 1600000) {
            float4 v = ((const float4*)x)[i];
            int pk = __builtin_amdgcn_cvt_pk_fp8_f32(v.x, v.y, 0, false);
            pk = __builtin_amdgcn_cvt_pk_fp8_f32(v.z, v.w, pk, true);
            ((unsigned*)x8)[i] = (unsigned)pk;
        }
    } else if (b < 6506) {
        int n = b - 6250;
        if (t < 128) Wt1[n * 128 + t] = (ushort)bf16u(W1[t * 256 + n]);
    } else {
        int n = b - 6506;
        Wt2[n * 256 + t] = (ushort)bf16u(W2[t * 256 + n]);
    }
}

// --------------- pass A: bin edges by 256-node bucket (dst>>8) --------------
// Per block: 2048 edges. LDS counting-group by bucket, reserve a run in the
// bucket's fixed-capacity stage region (one atomic per touched bucket on a
// 196-counter L2-hot array), write coalesced (packed,dst) runs.
// Also zeroes g[128*256] for the pooling atomics much later.
__global__ __launch_bounds__(256) void bin_pass(
    const int* __restrict__ src, const int* __restrict__ dst,
    const float* __restrict__ w, int* __restrict__ bcnt,
    uint2* __restrict__ stage, float* __restrict__ g, int E)
{
    __shared__ int hist[256];
    __shared__ int excl[256];
    __shared__ int gbase[256];
    __shared__ uint2 stg[2048];

    int t = threadIdx.x, b = blockIdx.x;
    if (b < 128) g[b * 256 + t] = 0.f;

    int e0 = b * 2048;
    hist[t] = 0;
    __syncthreads();

    int d_[8]; unsigned pk_[8]; int rk_[8]; int bk_[8];
    #pragma unroll
    for (int j = 0; j < 8; j++) {
        int e = e0 + t + j * 256;               // coalesced
        if (e < E) {
            int d = dst[e];
            d_[j] = d;
            bk_[j] = d >> 8;
            pk_[j] = (unsigned)src[e] | (bf16u(w[e]) << 16);
            rk_[j] = atomicAdd(&hist[bk_[j]], 1);
        } else d_[j] = -1;
    }
    __syncthreads();

    int cnt = hist[t];
    excl[t] = cnt;
    __syncthreads();
    for (int o = 1; o < 256; o <<= 1) {         // inclusive scan
        int v = (t >= o) ? excl[t - o] : 0;
        __syncthreads();
        excl[t] += v;
        __syncthreads();
    }
    int ex = excl[t] - cnt;                     // exclusive
    if (cnt > 0) gbase[t] = atomicAdd(&bcnt[t], cnt);   // reserve run
    __syncthreads();
    excl[t] = ex;
    __syncthreads();

    #pragma unroll
    for (int j = 0; j < 8; j++)
        if (d_[j] >= 0)
            stg[excl[bk_[j]] + rk_[j]] = make_uint2(pk_[j], (unsigned)d_[j]);
    __syncthreads();

    int nval = min(2048, E - e0);
    #pragma unroll
    for (int j = 0; j < 8; j++) {
        int sidx = t + j * 256;                 // consecutive lanes -> consecutive gpos
        if (sidx < nval) {
            uint2 ent = stg[sidx];
            int bk = (int)(ent.y >> 8);
            stage[(size_t)bk * BKT_CAP + gbase[bk] + sidx - excl[bk]] = ent;
        }
    }
}

// ------ pass B: per-bucket histogram + scan -> off[], sort -> edges[] -------
// One block per bucket. Bucket base = reduce over bcnt[0..b-1] (196 ints,
// L2-hot). LDS histogram of dst low byte gives per-node degrees -> off[]
// written directly (no global deg array, no global scan). Rank into a fully
// sorted LDS image, stream edges[] out linearly coalesced.
__global__ __launch_bounds__(256) void sort_build(
    const uint2* __restrict__ stage, const int* __restrict__ bcnt,
    unsigned* __restrict__ edges, int* __restrict__ off, int N, int E)
{
    __shared__ unsigned sorted[BKT_CAP];        // 24 KB
    __shared__ int hist[256];
    __shared__ int s[256];
    __shared__ int cur[256];
    __shared__ int psum[4];
    __shared__ int sbase;

    int t = threadIdx.x, b = blockIdx.x;
    const uint2* reg = stage + (size_t)b * BKT_CAP;
    int cnt = bcnt[b];

    // bucket base = sum of bcnt[0..b-1]
    int pred = (t < b) ? bcnt[t] : 0;
    #pragma unroll
    for (int o = 32; o > 0; o >>= 1) pred += __shfl_down(pred, o, 64);
    if ((t & 63) == 0) psum[t >> 6] = pred;
    hist[t] = 0;
    __syncthreads();
    if (t == 0) sbase = psum[0] + psum[1] + psum[2] + psum[3];

    for (int i = t; i < cnt; i += 256)
        atomicAdd(&hist[reg[i].y & 255u], 1);   // LDS atomic
    __syncthreads();

    int h = hist[t];
    s[t] = h;
    __syncthreads();
    for (int o = 1; o < 256; o <<= 1) {         // inclusive scan
        int v = (t >= o) ? s[t - o] : 0;
        __syncthreads();
        s[t] += v;
        __syncthreads();
    }
    int ex = s[t] - h;                          // exclusive
    cur[t] = ex;
    __syncthreads();

    int nn = b * 256 + t;
    if (nn <= N) off[nn] = sbase + ex;          // nn==N lands off[N]=E exactly

    for (int i = t; i < cnt; i += 256) {
        uint2 ent = reg[i];
        int r = atomicAdd(&cur[ent.y & 255u], 1);
        sorted[r] = ent.x;
    }
    __syncthreads();
    for (int i = t; i < cnt; i += 256)
        edges[sbase + i] = sorted[i];
}

// --------------- gather SpMM layer 1: fp8 e4m3 in, bf16 out -----------------
// x8 rows are 128B (128 x fp8); one ushort gather per edge per lane (two
// fully-used 64B lines per row), hw cvt_pk_f32_fp8 unpacks 2 features.
__global__ __launch_bounds__(256) void spmm128(
    const unsigned char* __restrict__ x8, const int* __restrict__ off,
    const unsigned* __restrict__ edges, ushort* __restrict__ S, int n)
{
    int node = blockIdx.x * 4 + (threadIdx.x >> 6);
    if (node >= n) return;
    int lane = threadIdx.x & 63;
    const ushort* base = (const ushort*)x8;   // row stride 64 ushorts (128B)
    int e0 = off[node], e1 = off[node + 1];
    float a0 = 0.f, a1 = 0.f;
    int e = e0;
    for (; e + 4 <= e1; e += 4) {
        unsigned ed0 = edges[e],     ed1 = edges[e + 1];
        unsigned ed2 = edges[e + 2], ed3 = edges[e + 3];
        float w0 = bfhi(ed0), w1 = bfhi(ed1);
        float w2 = bfhi(ed2), w3 = bfhi(ed3);
        ushort v0 = base[(size_t)(ed0 & 0xffffu) * 64 + lane];
        ushort v1 = base[(size_t)(ed1 & 0xffffu) * 64 + lane];
        ushort v2 = base[(size_t)(ed2 & 0xffffu) * 64 + lane];
        ushort v3 = base[(size_t)(ed3 & 0xffffu) * 64 + lane];
        v2f f0 = __builtin_amdgcn_cvt_pk_f32_fp8((int)v0, false);
        v2f f1 = __builtin_amdgcn_cvt_pk_f32_fp8((int)v1, false);
        v2f f2 = __builtin_amdgcn_cvt_pk_f32_fp8((int)v2, false);
        v2f f3 = __builtin_amdgcn_cvt_pk_f32_fp8((int)v3, false);
        a0 += f0.x * w0 + f1.x * w1 + f2.x * w2 + f3.x * w3;
        a1 += f0.y * w0 + f1.y * w1 + f2.y * w2 + f3.y * w3;
    }
    for (; e < e1; e++) {
        unsigned ed = edges[e];
        float w0 = bfhi(ed);
        ushort v0 = base[(size_t)(ed & 0xffffu) * 64 + lane];
        v2f f0 = __builtin_amdgcn_cvt_pk_f32_fp8((int)v0, false);
        a0 += f0.x * w0;
        a1 += f0.y * w0;
    }
    ((unsigned*)S)[(size_t)node * 64 + lane] = (bf16u(a1) << 16) | bf16u(a0);
}

// --------------- gather SpMM layer 2: fp8 e4m3 in, bf16 out -----------------
__global__ __launch_bounds__(256) void spmm256(
    const unsigned char* __restrict__ h8, const int* __restrict__ off,
    const unsigned* __restrict__ edges, ushort* __restrict__ S, int n)
{
    int node = blockIdx.x * 4 + (threadIdx.x >> 6);
    if (node >= n) return;
    int lane = threadIdx.x & 63;
    const unsigned* base = (const unsigned*)h8;    // row stride 64 uints (256B)
    int e0 = off[node], e1 = off[node + 1];
    float a0 = 0.f, a1 = 0.f, a2 = 0.f, a3 = 0.f;
    int e = e0;
    for (; e + 4 <= e1; e += 4) {
        unsigned ed0 = edges[e],     ed1 = edges[e + 1];
        unsigned ed2 = edges[e + 2], ed3 = edges[e + 3];
        float w0 = bfhi(ed0), w1 = bfhi(ed1);
        float w2 = bfhi(ed2), w3 = bfhi(ed3);
        unsigned v0 = base[(size_t)(ed0 & 0xffffu) * 64 + lane];
        unsigned v1 = base[(size_t)(ed1 & 0xffffu) * 64 + lane];
        unsigned v2 = base[(size_t)(ed2 & 0xffffu) * 64 + lane];
        unsigned v3 = base[(size_t)(ed3 & 0xffffu) * 64 + lane];
        v2f l0 = __builtin_amdgcn_cvt_pk_f32_fp8((int)v0, false);
        v2f h0 = __builtin_amdgcn_cvt_pk_f32_fp8((int)v0, true);
        v2f l1 = __builtin_amdgcn_cvt_pk_f32_fp8((int)v1, false);
        v2f h1v = __builtin_amdgcn_cvt_pk_f32_fp8((int)v1, true);
        v2f l2 = __builtin_amdgcn_cvt_pk_f32_fp8((int)v2, false);
        v2f h2 = __builtin_amdgcn_cvt_pk_f32_fp8((int)v2, true);
        v2f l3 = __builtin_amdgcn_cvt_pk_f32_fp8((int)v3, false);
        v2f h3 = __builtin_amdgcn_cvt_pk_f32_fp8((int)v3, true);
        a0 += l0.x * w0 + l1.x * w1 + l2.x * w2 + l3.x * w3;
        a1 += l0.y * w0 + l1.y * w1 + l2.y * w2 + l3.y * w3;
        a2 += h0.x * w0 + h1v.x * w1 + h2.x * w2 + h3.x * w3;
        a3 += h0.y * w0 + h1v.y * w1 + h2.y * w2 + h3.y * w3;
    }
    for (; e < e1; e++) {
        unsigned ed = edges[e];
        float w0 = bfhi(ed);
        unsigned v0 = base[(size_t)(ed & 0xffffu) * 64 + lane];
        v2f l0 = __builtin_amdgcn_cvt_pk_f32_fp8((int)v0, false);
        v2f h0 = __builtin_amdgcn_cvt_pk_f32_fp8((int)v0, true);
        a0 += l0.x * w0;
        a1 += l0.y * w0;
        a2 += h0.x * w0;
        a3 += h0.y * w0;
    }
    uint2 o;
    o.x = (bf16u(a1) << 16) | bf16u(a0);
    o.y = (bf16u(a3) << 16) | bf16u(a2);
    ((uint2*)S)[(size_t)node * 64 + lane] = o;
}

// ----------------- LDS-tiled MFMA bf16 GEMM, 128x256 tile -------------------
// 512 threads = 8 waves (2 row-halves x 4 col-quarters), BK=32.
// OFMT: 0=f32, 1=bf16, 2=fp8 e4m3. POOL=true: segment-pool into g via atomics.
template <int K, int OFMT, bool POOL>
__global__ __launch_bounds__(512) void gemm_tile(
    const ushort* __restrict__ A, const ushort* __restrict__ Wt,
    const float* __restrict__ bias, void* __restrict__ out,
    const int* __restrict__ seg, float* __restrict__ g, int M)
{
    __shared__ __align__(16) ushort As[128 * 32];   // 8 KB
    __shared__ __align__(16) ushort Bs[256 * 32];   // 16 KB
    __shared__ int segsh[128];

    const int tid = threadIdx.x;
    const int bm = blockIdx.x * 128;
    const int wave = tid >> 6, lane = tid & 63;
    const int wm = wave >> 2, wn = wave & 3;
    const int r = lane & 15, q = lane >> 4;

    if (POOL && tid < 128) {
        int gr = bm + tid;
        segsh[tid] = (gr < M) ? seg[gr] : 0x7fffffff;   // sentinel
    }

    const int o0 = tid * 16;           // 0..8191
    const int row0 = o0 >> 6;          // 0..127
    const int kb0 = o0 & 63;

    const char* Ab = (const char*)A;
    const char* Bb = (const char*)Wt;

    uint4 ra0, rb0, rb1;
    ra0 = *(const uint4*)(Ab + ((size_t)(bm + row0) * K) * 2 + kb0);
    rb0 = *(const uint4*)(Bb + ((size_t)(row0)       * K) * 2 + kb0);
    rb1 = *(const uint4*)(Bb + ((size_t)(row0 + 128) * K) * 2 + kb0);

    v4f acc[4][4];
    #pragma unroll
    for (int i = 0; i < 4; i++)
        #pragma unroll
        for (int j = 0; j < 4; j++) acc[i][j] = (v4f){0.f, 0.f, 0.f, 0.f};

    const int NK = K / 32;
    for (int ks = 0; ks < NK; ks++) {
        __syncthreads();
        *(uint4*)((char*)As + o0)        = ra0;
        *(uint4*)((char*)Bs + o0)        = rb0;
        *(uint4*)((char*)Bs + o0 + 8192) = rb1;
        if (ks + 1 < NK) {
            const int kof = (ks + 1) * 64;
            ra0 = *(const uint4*)(Ab + ((size_t)(bm + row0) * K) * 2 + kof + kb0);
            rb0 = *(const uint4*)(Bb + ((size_t)(row0)       * K) * 2 + kof + kb0);
            rb1 = *(const uint4*)(Bb + ((size_t)(row0 + 128) * K) * 2 + kof + kb0);
        }
        __syncthreads();

        v8s af[4], bf[4];
        #pragma unroll
        for (int i = 0; i < 4; i++)
            af[i] = *(const v8s*)(As + (wm * 64 + i * 16 + r) * 32 + q * 8);
        #pragma unroll
        for (int j = 0; j < 4; j++)
            bf[j] = *(const v8s*)(Bs + (wn * 64 + j * 16 + r) * 32 + q * 8);
        #pragma unroll
        for (int i = 0; i < 4; i++)
            #pragma unroll
            for (int j = 0; j < 4; j++)
                acc[i][j] = __builtin_amdgcn_mfma_f32_16x16x32_bf16(
                    af[i], bf[j], acc[i][j], 0, 0, 0);
    }

    if constexpr (POOL) {
        #pragma unroll
        for (int j = 0; j < 4; j++) {
            float b = bias[wn * 64 + j * 16 + r];
            #pragma unroll
            for (int i = 0; i < 4; i++)
                #pragma unroll
                for (int ii = 0; ii < 4; ii++)
                    acc[i][j][ii] = fmaxf(acc[i][j][ii] + b, 0.f);
        }
        int myseg[16];
        #pragma unroll
        for (int i = 0; i < 4; i++)
            #pragma unroll
            for (int ii = 0; ii < 4; ii++)
                myseg[i * 4 + ii] = segsh[wm * 64 + i * 16 + q * 4 + ii];
        int s_lo = segsh[0];
        int s_hi = segsh[min(127, M - 1 - bm)];
        for (int s = s_lo; s <= s_hi; s++) {
            #pragma unroll
            for (int j = 0; j < 4; j++) {
                float p = 0.f;
                #pragma unroll
                for (int i = 0; i < 4; i++)
                    #pragma unroll
                    for (int ii = 0; ii < 4; ii++)
                        if (myseg[i * 4 + ii] == s) p += acc[i][j][ii];
                p += __shfl_xor(p, 16, 64);
                p += __shfl_xor(p, 32, 64);
                if (lane < 16)
                    atomicAdd(&g[s * 256 + wn * 64 + j * 16 + r], p);
            }
        }
    } else {
        #pragma unroll
        for (int j = 0; j < 4; j++) {
            int col = wn * 64 + j * 16 + r;
            float b = bias[col];
            #pragma unroll
            for (int i = 0; i < 4; i++) {
                #pragma unroll
                for (int ii = 0; ii < 4; ii++) {
                    int row = bm + wm * 64 + i * 16 + q * 4 + ii;
                    if (row < M) {
                        float v = fmaxf(acc[i][j][ii] + b, 0.f);
                        if constexpr (OFMT == 1) {
                            ((ushort*)out)[(size_t)row * 256 + col] = (ushort)bf16u(v);
                        } else if constexpr (OFMT == 2) {
                            unsigned pk = (unsigned)__builtin_amdgcn_cvt_pk_fp8_f32(
                                v, v, 0, false);
                            ((unsigned char*)out)[(size_t)row * 256 + col] =
                                (unsigned char)(pk & 0xffu);
                        } else {
                            ((float*)out)[(size_t)row * 256 + col] = v;
                        }
                    }
                }
            }
        }
    }
}

// ---------------------------------- head ------------------------------------
__global__ __launch_bounds__(256) void head(
    const float* __restrict__ g, const float* __restrict__ Wd,
    const float* __restrict__ bd, const float* __restrict__ Wo,
    const float* __restrict__ bo, float* __restrict__ out)
{
    __shared__ float gr[256];
    int j = threadIdx.x;
    int gi = blockIdx.x;
    gr[j] = g[(size_t)gi * 256 + j];
    __syncthreads();
    float a2 = bd[j];
    for (int k = 0; k < 256; k++)
        a2 += gr[k] * Wd[(size_t)k * 256 + j];
    a2 = fmaxf(a2, 0.f);

    float v = a2 * Wo[j];
    #pragma unroll
    for (int off = 32; off > 0; off >>= 1)
        v += __shfl_down(v, off, 64);
    __shared__ float partial[4];
    if ((j & 63) == 0) partial[j >> 6] = v;
    __syncthreads();
    if (j == 0)
        out[gi] = partial[0] + partial[1] + partial[2] + partial[3] + bo[0];
}

extern "C" void kernel_launch(void* const* d_in, const int* in_sizes, int n_in,
                              void* d_out, int out_size, void* d_ws, size_t ws_size,
                              hipStream_t stream) {
    const float* x   = (const float*)d_in[0];
    const int*   esrc= (const int*)  d_in[1];
    const int*   edst= (const int*)  d_in[2];
    const float* ew  = (const float*)d_in[3];
    const int*   seg = (const int*)  d_in[4];
    const float* W1  = (const float*)d_in[5];
    const float* b1  = (const float*)d_in[6];
    const float* W2  = (const float*)d_in[7];
    const float* b2  = (const float*)d_in[8];
    const float* Wd  = (const float*)d_in[9];
    const float* bd  = (const float*)d_in[10];
    const float* Wo  = (const float*)d_in[11];
    const float* bo  = (const float*)d_in[12];
    float* out = (float*)d_out;

    const int N = 50000, E = 800000, G = 128, H = 256, F = 128;
    const int NPAD = 50048;            // 391 * 128
    const int NB = (N + 255) / 256;    // 196 (= bucket count)

    // workspace; region0 reused: {x8, S1, stage}; stage dies before spmm128
    char* p = (char*)d_ws;
    char* region0 = p;                  p += (size_t)N * H * sizeof(float);    // 51.2 MB
    unsigned char* x8 = (unsigned char*)region0;                               // [N,128] fp8
    ushort* S1 = (ushort*)(region0 + (size_t)N * F);                           // [NPAD,128] bf16
    uint2* stage = (uint2*)(region0 + (size_t)32 * 1024 * 1024);               // 196*6144*8B = 9.6MB
    unsigned char* h8 = (unsigned char*)p;
                                        p += (size_t)N * H;                    // [N,256] fp8
    ushort* S2 = (ushort*)p;            p += (size_t)NPAD * H * sizeof(ushort);// [NPAD,256] bf16
    float* g   = (float*)p;             p += (size_t)G * H * sizeof(float);
    int*   bcnt= (int*)p;               p += 256 * sizeof(int);                // bucket counts
    int*   off = (int*)p;               p += (size_t)(N + 1) * sizeof(int) + 12;
    unsigned* edges=(unsigned*)p;       p += (size_t)E * sizeof(unsigned);     // packed 4B (src,w)
    ushort* Wt1= (ushort*)p;            p += (size_t)H * F * sizeof(ushort);   // [256,128]
    ushort* Wt2= (ushort*)p;            p += (size_t)H * H * sizeof(ushort);   // [256,256]

    // ---- prep (x->fp8, W^T) + binned CSR build (no deg, no global scan) ----
    hipMemsetAsync(bcnt, 0, 256 * sizeof(int), stream);
    prep<<<6762, 256, 0, stream>>>(x, x8, W1, Wt1, W2, Wt2);
    bin_pass<<<(E + 2047) / 2048, 256, 0, stream>>>(esrc, edst, ew, bcnt, stage, g, E);
    sort_build<<<NB, 256, 0, stream>>>(stage, bcnt, edges, off, N, E);

    // ---- layer 1: S1 = A@x ; h8 = fp8(relu(S1@W1 + b1)) ----
    spmm128<<<(N + 3) / 4, 256, 0, stream>>>(x8, off, edges, S1, N);
    gemm_tile<128, 2, false><<<NPAD / 128, 512, 0, stream>>>(
        S1, Wt1, b1, h8, nullptr, nullptr, N);

    // ---- layer 2: S2 = A@h8 ; pool(relu(S2@W2+b2)) fused into epilogue ----
    spmm256<<<(N + 3) / 4, 256, 0, stream>>>(h8, off, edges, S2, N);
    gemm_tile<256, 0, true><<<NPAD / 128, 512, 0, stream>>>(
        S2, Wt2, b2, nullptr, seg, g, N);

    // ---- head ----
    head<<<G, 256, 0, stream>>>(g, Wd, bd, Wo, bo, out);
}

// Round 5
// 228.225 us; speedup vs baseline: 1.3885x; 1.0535x over previous
//
#include <hip/hip_runtime.h>
#include <hip/hip_bf16.h>

// ---------------------------------------------------------------------------
// TwoLayerGCN. Round 21: 8-deep gather pipeline in both spmm kernels.
// R20 post-mortem: fp8-x predicted -16us, got -3.4 -> gathers are NOT
// bytes-bound. R16 signature (VALUBusy 32%, occ 65%, 45% BW) = latency/MLP
// bound: 4 outstanding gathers/wave x 8 waves/SIMD = 32 in flight, too few
// to cover ~600-900cy L2-miss latency; shrinking rows (R17/R20) reduced
// lines-in-flight per load and under-delivered. Fix: 8 gathers in flight
// (dedicated load block, then consume; 4-deep mid + scalar tail for
// Poisson(16) degrees). VGPR 20->~40, no occupancy cost. Predict spmm256
// ~35->26us (FETCH unchanged ~90MB, VALUBusy ->~45%), spmm128 -4us,
// total 240->~224us, absmax 0.75 unchanged. If NULL: gathers are
// issue-rate-bound -> next lever is spmm->gemm fusion (kill S2 roundtrip).
// fp8 x/h1 (R17/R20) + binned build (R18) + fused off[] (R19) retained.
// ---------------------------------------------------------------------------

typedef short v8s __attribute__((ext_vector_type(8)));
typedef float v4f __attribute__((ext_vector_type(4)));
typedef float v2f __attribute__((ext_vector_type(2)));

#define BKT_CAP 6144   // stage capacity per 256-node bucket (mean 4096, std 64)

__device__ inline unsigned bf16u(float f) {           // fp32 -> bf16 bits (RNE)
    unsigned u = __builtin_bit_cast(unsigned, f);
    return (u + 0x7fffu + ((u >> 16) & 1u)) >> 16;
}
__device__ inline float bflo(unsigned v) { return __builtin_bit_cast(float, v << 16); }
__device__ inline float bfhi(unsigned v) { return __builtin_bit_cast(float, v & 0xffff0000u); }

// ---------------------- fused prep: x->fp8, W^T -----------------------------
__global__ __launch_bounds__(256) void prep(
    const float* __restrict__ x, unsigned char* __restrict__ x8,
    const float* __restrict__ W1, ushort* __restrict__ Wt1,
    const float* __restrict__ W2, ushort* __restrict__ Wt2)
{
    int b = blockIdx.x;
    int t = threadIdx.x;
    if (b < 6250) {
        int i = b * 256 + t;                 // n4 = 1600000
        if (i < 1600000) {
            float4 v = ((const float4*)x)[i];
            int pk = __builtin_amdgcn_cvt_pk_fp8_f32(v.x, v.y, 0, false);
            pk = __builtin_amdgcn_cvt_pk_fp8_f32(v.z, v.w, pk, true);
            ((unsigned*)x8)[i] = (unsigned)pk;
        }
    } else if (b < 6506) {
        int n = b - 6250;
        if (t < 128) Wt1[n * 128 + t] = (ushort)bf16u(W1[t * 256 + n]);
    } else {
        int n = b - 6506;
        Wt2[n * 256 + t] = (ushort)bf16u(W2[t * 256 + n]);
    }
}

// --------------- pass A: bin edges by 256-node bucket (dst>>8) --------------
__global__ __launch_bounds__(256) void bin_pass(
    const int* __restrict__ src, const int* __restrict__ dst,
    const float* __restrict__ w, int* __restrict__ bcnt,
    uint2* __restrict__ stage, float* __restrict__ g, int E)
{
    __shared__ int hist[256];
    __shared__ int excl[256];
    __shared__ int gbase[256];
    __shared__ uint2 stg[2048];

    int t = threadIdx.x, b = blockIdx.x;
    if (b < 128) g[b * 256 + t] = 0.f;

    int e0 = b * 2048;
    hist[t] = 0;
    __syncthreads();

    int d_[8]; unsigned pk_[8]; int rk_[8]; int bk_[8];
    #pragma unroll
    for (int j = 0; j < 8; j++) {
        int e = e0 + t + j * 256;               // coalesced
        if (e < E) {
            int d = dst[e];
            d_[j] = d;
            bk_[j] = d >> 8;
            pk_[j] = (unsigned)src[e] | (bf16u(w[e]) << 16);
            rk_[j] = atomicAdd(&hist[bk_[j]], 1);
        } else d_[j] = -1;
    }
    __syncthreads();

    int cnt = hist[t];
    excl[t] = cnt;
    __syncthreads();
    for (int o = 1; o < 256; o <<= 1) {         // inclusive scan
        int v = (t >= o) ? excl[t - o] : 0;
        __syncthreads();
        excl[t] += v;
        __syncthreads();
    }
    int ex = excl[t] - cnt;                     // exclusive
    if (cnt > 0) gbase[t] = atomicAdd(&bcnt[t], cnt);   // reserve run
    __syncthreads();
    excl[t] = ex;
    __syncthreads();

    #pragma unroll
    for (int j = 0; j < 8; j++)
        if (d_[j] >= 0)
            stg[excl[bk_[j]] + rk_[j]] = make_uint2(pk_[j], (unsigned)d_[j]);
    __syncthreads();

    int nval = min(2048, E - e0);
    #pragma unroll
    for (int j = 0; j < 8; j++) {
        int sidx = t + j * 256;                 // consecutive lanes -> consecutive gpos
        if (sidx < nval) {
            uint2 ent = stg[sidx];
            int bk = (int)(ent.y >> 8);
            stage[(size_t)bk * BKT_CAP + gbase[bk] + sidx - excl[bk]] = ent;
        }
    }
}

// ------ pass B: per-bucket histogram + scan -> off[], sort -> edges[] -------
__global__ __launch_bounds__(256) void sort_build(
    const uint2* __restrict__ stage, const int* __restrict__ bcnt,
    unsigned* __restrict__ edges, int* __restrict__ off, int N, int E)
{
    __shared__ unsigned sorted[BKT_CAP];        // 24 KB
    __shared__ int hist[256];
    __shared__ int s[256];
    __shared__ int cur[256];
    __shared__ int psum[4];
    __shared__ int sbase;

    int t = threadIdx.x, b = blockIdx.x;
    const uint2* reg = stage + (size_t)b * BKT_CAP;
    int cnt = bcnt[b];

    // bucket base = sum of bcnt[0..b-1]
    int pred = (t < b) ? bcnt[t] : 0;
    #pragma unroll
    for (int o = 32; o > 0; o >>= 1) pred += __shfl_down(pred, o, 64);
    if ((t & 63) == 0) psum[t >> 6] = pred;
    hist[t] = 0;
    __syncthreads();
    if (t == 0) sbase = psum[0] + psum[1] + psum[2] + psum[3];

    for (int i = t; i < cnt; i += 256)
        atomicAdd(&hist[reg[i].y & 255u], 1);   // LDS atomic
    __syncthreads();

    int h = hist[t];
    s[t] = h;
    __syncthreads();
    for (int o = 1; o < 256; o <<= 1) {         // inclusive scan
        int v = (t >= o) ? s[t - o] : 0;
        __syncthreads();
        s[t] += v;
        __syncthreads();
    }
    int ex = s[t] - h;                          // exclusive
    cur[t] = ex;
    __syncthreads();

    int nn = b * 256 + t;
    if (nn <= N) off[nn] = sbase + ex;          // nn==N lands off[N]=E exactly

    for (int i = t; i < cnt; i += 256) {
        uint2 ent = reg[i];
        int r = atomicAdd(&cur[ent.y & 255u], 1);
        sorted[r] = ent.x;
    }
    __syncthreads();
    for (int i = t; i < cnt; i += 256)
        edges[sbase + i] = sorted[i];
}

// --------------- gather SpMM layer 1: fp8 e4m3 in, bf16 out -----------------
// 8-deep gather pipeline: issue 8 row loads back-to-back, then consume.
__global__ __launch_bounds__(256) void spmm128(
    const unsigned char* __restrict__ x8, const int* __restrict__ off,
    const unsigned* __restrict__ edges, ushort* __restrict__ S, int n)
{
    int node = blockIdx.x * 4 + (threadIdx.x >> 6);
    if (node >= n) return;
    int lane = threadIdx.x & 63;
    const ushort* base = (const ushort*)x8;   // row stride 64 ushorts (128B)
    int e0 = off[node], e1 = off[node + 1];
    float a0 = 0.f, a1 = 0.f;
    int e = e0;
    for (; e + 8 <= e1; e += 8) {
        unsigned ed[8]; ushort v[8];
        #pragma unroll
        for (int j = 0; j < 8; j++) ed[j] = edges[e + j];
        #pragma unroll
        for (int j = 0; j < 8; j++)
            v[j] = base[(size_t)(ed[j] & 0xffffu) * 64 + lane];
        #pragma unroll
        for (int j = 0; j < 8; j++) {
            float w = bfhi(ed[j]);
            v2f f = __builtin_amdgcn_cvt_pk_f32_fp8((int)v[j], false);
            a0 += f.x * w;
            a1 += f.y * w;
        }
    }
    for (; e + 4 <= e1; e += 4) {
        unsigned ed[4]; ushort v[4];
        #pragma unroll
        for (int j = 0; j < 4; j++) ed[j] = edges[e + j];
        #pragma unroll
        for (int j = 0; j < 4; j++)
            v[j] = base[(size_t)(ed[j] & 0xffffu) * 64 + lane];
        #pragma unroll
        for (int j = 0; j < 4; j++) {
            float w = bfhi(ed[j]);
            v2f f = __builtin_amdgcn_cvt_pk_f32_fp8((int)v[j], false);
            a0 += f.x * w;
            a1 += f.y * w;
        }
    }
    for (; e < e1; e++) {
        unsigned ed = edges[e];
        float w0 = bfhi(ed);
        ushort v0 = base[(size_t)(ed & 0xffffu) * 64 + lane];
        v2f f0 = __builtin_amdgcn_cvt_pk_f32_fp8((int)v0, false);
        a0 += f0.x * w0;
        a1 += f0.y * w0;
    }
    ((unsigned*)S)[(size_t)node * 64 + lane] = (bf16u(a1) << 16) | bf16u(a0);
}

// --------------- gather SpMM layer 2: fp8 e4m3 in, bf16 out -----------------
// 8-deep gather pipeline.
__global__ __launch_bounds__(256) void spmm256(
    const unsigned char* __restrict__ h8, const int* __restrict__ off,
    const unsigned* __restrict__ edges, ushort* __restrict__ S, int n)
{
    int node = blockIdx.x * 4 + (threadIdx.x >> 6);
    if (node >= n) return;
    int lane = threadIdx.x & 63;
    const unsigned* base = (const unsigned*)h8;    // row stride 64 uints (256B)
    int e0 = off[node], e1 = off[node + 1];
    float a0 = 0.f, a1 = 0.f, a2 = 0.f, a3 = 0.f;
    int e = e0;
    for (; e + 8 <= e1; e += 8) {
        unsigned ed[8]; unsigned v[8];
        #pragma unroll
        for (int j = 0; j < 8; j++) ed[j] = edges[e + j];
        #pragma unroll
        for (int j = 0; j < 8; j++)
            v[j] = base[(size_t)(ed[j] & 0xffffu) * 64 + lane];
        #pragma unroll
        for (int j = 0; j < 8; j++) {
            float w = bfhi(ed[j]);
            v2f l = __builtin_amdgcn_cvt_pk_f32_fp8((int)v[j], false);
            v2f h = __builtin_amdgcn_cvt_pk_f32_fp8((int)v[j], true);
            a0 += l.x * w;
            a1 += l.y * w;
            a2 += h.x * w;
            a3 += h.y * w;
        }
    }
    for (; e + 4 <= e1; e += 4) {
        unsigned ed[4]; unsigned v[4];
        #pragma unroll
        for (int j = 0; j < 4; j++) ed[j] = edges[e + j];
        #pragma unroll
        for (int j = 0; j < 4; j++)
            v[j] = base[(size_t)(ed[j] & 0xffffu) * 64 + lane];
        #pragma unroll
        for (int j = 0; j < 4; j++) {
            float w = bfhi(ed[j]);
            v2f l = __builtin_amdgcn_cvt_pk_f32_fp8((int)v[j], false);
            v2f h = __builtin_amdgcn_cvt_pk_f32_fp8((int)v[j], true);
            a0 += l.x * w;
            a1 += l.y * w;
            a2 += h.x * w;
            a3 += h.y * w;
        }
    }
    for (; e < e1; e++) {
        unsigned ed = edges[e];
        float w0 = bfhi(ed);
        unsigned v0 = base[(size_t)(ed & 0xffffu) * 64 + lane];
        v2f l0 = __builtin_amdgcn_cvt_pk_f32_fp8((int)v0, false);
        v2f h0 = __builtin_amdgcn_cvt_pk_f32_fp8((int)v0, true);
        a0 += l0.x * w0;
        a1 += l0.y * w0;
        a2 += h0.x * w0;
        a3 += h0.y * w0;
    }
    uint2 o;
    o.x = (bf16u(a1) << 16) | bf16u(a0);
    o.y = (bf16u(a3) << 16) | bf16u(a2);
    ((uint2*)S)[(size_t)node * 64 + lane] = o;
}

// ----------------- LDS-tiled MFMA bf16 GEMM, 128x256 tile -------------------
// 512 threads = 8 waves (2 row-halves x 4 col-quarters), BK=32.
// OFMT: 0=f32, 1=bf16, 2=fp8 e4m3. POOL=true: segment-pool into g via atomics.
template <int K, int OFMT, bool POOL>
__global__ __launch_bounds__(512) void gemm_tile(
    const ushort* __restrict__ A, const ushort* __restrict__ Wt,
    const float* __restrict__ bias, void* __restrict__ out,
    const int* __restrict__ seg, float* __restrict__ g, int M)
{
    __shared__ __align__(16) ushort As[128 * 32];   // 8 KB
    __shared__ __align__(16) ushort Bs[256 * 32];   // 16 KB
    __shared__ int segsh[128];

    const int tid = threadIdx.x;
    const int bm = blockIdx.x * 128;
    const int wave = tid >> 6, lane = tid & 63;
    const int wm = wave >> 2, wn = wave & 3;
    const int r = lane & 15, q = lane >> 4;

    if (POOL && tid < 128) {
        int gr = bm + tid;
        segsh[tid] = (gr < M) ? seg[gr] : 0x7fffffff;   // sentinel
    }

    const int o0 = tid * 16;           // 0..8191
    const int row0 = o0 >> 6;          // 0..127
    const int kb0 = o0 & 63;

    const char* Ab = (const char*)A;
    const char* Bb = (const char*)Wt;

    uint4 ra0, rb0, rb1;
    ra0 = *(const uint4*)(Ab + ((size_t)(bm + row0) * K) * 2 + kb0);
    rb0 = *(const uint4*)(Bb + ((size_t)(row0)       * K) * 2 + kb0);
    rb1 = *(const uint4*)(Bb + ((size_t)(row0 + 128) * K) * 2 + kb0);

    v4f acc[4][4];
    #pragma unroll
    for (int i = 0; i < 4; i++)
        #pragma unroll
        for (int j = 0; j < 4; j++) acc[i][j] = (v4f){0.f, 0.f, 0.f, 0.f};

    const int NK = K / 32;
    for (int ks = 0; ks < NK; ks++) {
        __syncthreads();
        *(uint4*)((char*)As + o0)        = ra0;
        *(uint4*)((char*)Bs + o0)        = rb0;
        *(uint4*)((char*)Bs + o0 + 8192) = rb1;
        if (ks + 1 < NK) {
            const int kof = (ks + 1) * 64;
            ra0 = *(const uint4*)(Ab + ((size_t)(bm + row0) * K) * 2 + kof + kb0);
            rb0 = *(const uint4*)(Bb + ((size_t)(row0)       * K) * 2 + kof + kb0);
            rb1 = *(const uint4*)(Bb + ((size_t)(row0 + 128) * K) * 2 + kof + kb0);
        }
        __syncthreads();

        v8s af[4], bf[4];
        #pragma unroll
        for (int i = 0; i < 4; i++)
            af[i] = *(const v8s*)(As + (wm * 64 + i * 16 + r) * 32 + q * 8);
        #pragma unroll
        for (int j = 0; j < 4; j++)
            bf[j] = *(const v8s*)(Bs + (wn * 64 + j * 16 + r) * 32 + q * 8);
        #pragma unroll
        for (int i = 0; i < 4; i++)
            #pragma unroll
            for (int j = 0; j < 4; j++)
                acc[i][j] = __builtin_amdgcn_mfma_f32_16x16x32_bf16(
                    af[i], bf[j], acc[i][j], 0, 0, 0);
    }

    if constexpr (POOL) {
        #pragma unroll
        for (int j = 0; j < 4; j++) {
            float b = bias[wn * 64 + j * 16 + r];
            #pragma unroll
            for (int i = 0; i < 4; i++)
                #pragma unroll
                for (int ii = 0; ii < 4; ii++)
                    acc[i][j][ii] = fmaxf(acc[i][j][ii] + b, 0.f);
        }
        int myseg[16];
        #pragma unroll
        for (int i = 0; i < 4; i++)
            #pragma unroll
            for (int ii = 0; ii < 4; ii++)
                myseg[i * 4 + ii] = segsh[wm * 64 + i * 16 + q * 4 + ii];
        int s_lo = segsh[0];
        int s_hi = segsh[min(127, M - 1 - bm)];
        for (int s = s_lo; s <= s_hi; s++) {
            #pragma unroll
            for (int j = 0; j < 4; j++) {
                float p = 0.f;
                #pragma unroll
                for (int i = 0; i < 4; i++)
                    #pragma unroll
                    for (int ii = 0; ii < 4; ii++)
                        if (myseg[i * 4 + ii] == s) p += acc[i][j][ii];
                p += __shfl_xor(p, 16, 64);
                p += __shfl_xor(p, 32, 64);
                if (lane < 16)
                    atomicAdd(&g[s * 256 + wn * 64 + j * 16 + r], p);
            }
        }
    } else {
        #pragma unroll
        for (int j = 0; j < 4; j++) {
            int col = wn * 64 + j * 16 + r;
            float b = bias[col];
            #pragma unroll
            for (int i = 0; i < 4; i++) {
                #pragma unroll
                for (int ii = 0; ii < 4; ii++) {
                    int row = bm + wm * 64 + i * 16 + q * 4 + ii;
                    if (row < M) {
                        float v = fmaxf(acc[i][j][ii] + b, 0.f);
                        if constexpr (OFMT == 1) {
                            ((ushort*)out)[(size_t)row * 256 + col] = (ushort)bf16u(v);
                        } else if constexpr (OFMT == 2) {
                            unsigned pk = (unsigned)__builtin_amdgcn_cvt_pk_fp8_f32(
                                v, v, 0, false);
                            ((unsigned char*)out)[(size_t)row * 256 + col] =
                                (unsigned char)(pk & 0xffu);
                        } else {
                            ((float*)out)[(size_t)row * 256 + col] = v;
                        }
                    }
                }
            }
        }
    }
}

// ---------------------------------- head ------------------------------------
__global__ __launch_bounds__(256) void head(
    const float* __restrict__ g, const float* __restrict__ Wd,
    const float* __restrict__ bd, const float* __restrict__ Wo,
    const float* __restrict__ bo, float* __restrict__ out)
{
    __shared__ float gr[256];
    int j = threadIdx.x;
    int gi = blockIdx.x;
    gr[j] = g[(size_t)gi * 256 + j];
    __syncthreads();
    float a2 = bd[j];
    for (int k = 0; k < 256; k++)
        a2 += gr[k] * Wd[(size_t)k * 256 + j];
    a2 = fmaxf(a2, 0.f);

    float v = a2 * Wo[j];
    #pragma unroll
    for (int off = 32; off > 0; off >>= 1)
        v += __shfl_down(v, off, 64);
    __shared__ float partial[4];
    if ((j & 63) == 0) partial[j >> 6] = v;
    __syncthreads();
    if (j == 0)
        out[gi] = partial[0] + partial[1] + partial[2] + partial[3] + bo[0];
}

extern "C" void kernel_launch(void* const* d_in, const int* in_sizes, int n_in,
                              void* d_out, int out_size, void* d_ws, size_t ws_size,
                              hipStream_t stream) {
    const float* x   = (const float*)d_in[0];
    const int*   esrc= (const int*)  d_in[1];
    const int*   edst= (const int*)  d_in[2];
    const float* ew  = (const float*)d_in[3];
    const int*   seg = (const int*)  d_in[4];
    const float* W1  = (const float*)d_in[5];
    const float* b1  = (const float*)d_in[6];
    const float* W2  = (const float*)d_in[7];
    const float* b2  = (const float*)d_in[8];
    const float* Wd  = (const float*)d_in[9];
    const float* bd  = (const float*)d_in[10];
    const float* Wo  = (const float*)d_in[11];
    const float* bo  = (const float*)d_in[12];
    float* out = (float*)d_out;

    const int N = 50000, E = 800000, G = 128, H = 256, F = 128;
    const int NPAD = 50048;            // 391 * 128
    const int NB = (N + 255) / 256;    // 196 (= bucket count)

    // workspace; region0 reused: {x8, S1, stage}; stage dies before spmm128
    char* p = (char*)d_ws;
    char* region0 = p;                  p += (size_t)N * H * sizeof(float);    // 51.2 MB
    unsigned char* x8 = (unsigned char*)region0;                               // [N,128] fp8
    ushort* S1 = (ushort*)(region0 + (size_t)N * F);                           // [NPAD,128] bf16
    uint2* stage = (uint2*)(region0 + (size_t)32 * 1024 * 1024);               // 196*6144*8B = 9.6MB
    unsigned char* h8 = (unsigned char*)p;
                                        p += (size_t)N * H;                    // [N,256] fp8
    ushort* S2 = (ushort*)p;            p += (size_t)NPAD * H * sizeof(ushort);// [NPAD,256] bf16
    float* g   = (float*)p;             p += (size_t)G * H * sizeof(float);
    int*   bcnt= (int*)p;               p += 256 * sizeof(int);                // bucket counts
    int*   off = (int*)p;               p += (size_t)(N + 1) * sizeof(int) + 12;
    unsigned* edges=(unsigned*)p;       p += (size_t)E * sizeof(unsigned);     // packed 4B (src,w)
    ushort* Wt1= (ushort*)p;            p += (size_t)H * F * sizeof(ushort);   // [256,128]
    ushort* Wt2= (ushort*)p;            p += (size_t)H * H * sizeof(ushort);   // [256,256]

    // ---- prep (x->fp8, W^T) + binned CSR build (no deg, no global scan) ----
    hipMemsetAsync(bcnt, 0, 256 * sizeof(int), stream);
    prep<<<6762, 256, 0, stream>>>(x, x8, W1, Wt1, W2, Wt2);
    bin_pass<<<(E + 2047) / 2048, 256, 0, stream>>>(esrc, edst, ew, bcnt, stage, g, E);
    sort_build<<<NB, 256, 0, stream>>>(stage, bcnt, edges, off, N, E);

    // ---- layer 1: S1 = A@x ; h8 = fp8(relu(S1@W1 + b1)) ----
    spmm128<<<(N + 3) / 4, 256, 0, stream>>>(x8, off, edges, S1, N);
    gemm_tile<128, 2, false><<<NPAD / 128, 512, 0, stream>>>(
        S1, Wt1, b1, h8, nullptr, nullptr, N);

    // ---- layer 2: S2 = A@h8 ; pool(relu(S2@W2+b2)) fused into epilogue ----
    spmm256<<<(N + 3) / 4, 256, 0, stream>>>(h8, off, edges, S2, N);
    gemm_tile<256, 0, true><<<NPAD / 128, 512, 0, stream>>>(
        S2, Wt2, b2, nullptr, seg, g, N);

    // ---- head ----
    head<<<G, 256, 0, stream>>>(g, Wd, bd, Wo, bo, out);
}